// Round 12
// baseline (829.319 us; speedup 1.0000x reference)
//
#include <hip/hip_runtime.h>
#include <hip/hip_bf16.h>
#include <hip/hip_cooperative_groups.h>
#include <stdint.h>

namespace cg = cooperative_groups;

typedef __attribute__((ext_vector_type(8))) short short8;
typedef __attribute__((ext_vector_type(4))) short short4v;
typedef __attribute__((ext_vector_type(4))) float floatx4;
typedef __hip_bfloat16 bf16;

__device__ __forceinline__ float b2f(bf16 v) { return __bfloat162float(v); }
__device__ __forceinline__ bf16 f2b(float v) { return __float2bfloat16(v); }
__device__ __forceinline__ float gelu_f(float v) {
    return 0.5f * v * (1.0f + erff(v * 0.70710678118654752f));
}

#define GLD_LDS16(gptr, lptr) \
  __builtin_amdgcn_global_load_lds((const __attribute__((address_space(1))) void*)(gptr), \
                                   (__attribute__((address_space(3))) void*)(lptr), 16, 0, 0)

// ---------------- cooperative: zero+transpose | count | scan | scatter ----------------
// 512 blocks x 256 threads. N=32768 (64 nodes/block), E=524288 (4 edges/thread).
__global__ __launch_bounds__(256) void k_csr(const int* __restrict__ dst,
                                             const int* __restrict__ src,
                                             int* __restrict__ cnt,
                                             int* __restrict__ row_ptr,
                                             int* __restrict__ fill,
                                             int* __restrict__ col, int E,
                                             const float* __restrict__ Wl1,
                                             const float* __restrict__ Wr1,
                                             const float* __restrict__ Wl2,
                                             const float* __restrict__ Wr2,
                                             bf16* __restrict__ Wt,
                                             int* __restrict__ btot) {
    cg::grid_group grid = cg::this_grid();
    int b = blockIdx.x, t = threadIdx.x;

    // phase 0: zero cnt (64 ints/block) + both layers' weight transposes (2 rows/block)
    if (t < 64) cnt[b * 64 + t] = 0;
    #pragma unroll
    for (int q = 0; q < 2; q++) {
        int u = b * 2 + q;                       // 0..1023 transpose units
        int r = u & 255, half = (u >> 8) & 1, layer = u >> 9;
        const float* W = layer ? (half ? Wr2 : Wl2) : (half ? Wr1 : Wl1);
        Wt[(size_t)(layer * 512 + half * 256 + t) * 256 + r] = f2b(W[r * 256 + t]);
    }
    grid.sync();

    // phase 1: count (4 edges/thread)
    {
        int g = b * 256 + t;
        if (g * 4 < E) {
            int4 d = ((const int4*)dst)[g];
            atomicAdd(&cnt[d.x], 1);
            atomicAdd(&cnt[d.y], 1);
            atomicAdd(&cnt[d.z], 1);
            atomicAdd(&cnt[d.w], 1);
        }
    }
    grid.sync();

    // phase 2a: per-block wave scan of this block's 64 counts (wave 0 only)
    int myCnt = 0, myPre = 0;
    if (t < 64) {
        myCnt = cnt[b * 64 + t];
        int v = myCnt;
        #pragma unroll
        for (int off = 1; off < 64; off <<= 1) {
            int u = __shfl_up(v, off, 64);
            if (t >= off) v += u;
        }
        myPre = v - myCnt;                       // exclusive within block
        if (t == 63) btot[b] = v;                // block total
    }
    grid.sync();

    // phase 2b: block 0 wave 0 scans the 512 block totals (8 per lane)
    if (b == 0 && t < 64) {
        int vals[8], pre[8], s = 0;
        #pragma unroll
        for (int q = 0; q < 8; q++) { vals[q] = btot[t * 8 + q]; pre[q] = s; s += vals[q]; }
        int v = s;
        #pragma unroll
        for (int off = 1; off < 64; off <<= 1) {
            int u = __shfl_up(v, off, 64);
            if (t >= off) v += u;
        }
        int excl = v - s;                        // exclusive prefix of lane's chunk
        #pragma unroll
        for (int q = 0; q < 8; q++) btot[t * 8 + q] = excl + pre[q];
        if (t == 63) row_ptr[512 * 64] = v;      // grand total = E
    }
    grid.sync();

    // phase 2c: write row_ptr/fill (registers persisted across syncs)
    if (t < 64) {
        int val = btot[b] + myPre;
        row_ptr[b * 64 + t] = val;
        fill[b * 64 + t] = val;
    }
    grid.sync();

    // phase 3: scatter (4 edges/thread)
    {
        int g = b * 256 + t;
        if (g * 4 < E) {
            int4 d = ((const int4*)dst)[g];
            int4 sv = ((const int4*)src)[g];
            int p;
            p = atomicAdd(&fill[d.x], 1); col[p] = sv.x;
            p = atomicAdd(&fill[d.y], 1); col[p] = sv.y;
            p = atomicAdd(&fill[d.z], 1); col[p] = sv.z;
            p = atomicAdd(&fill[d.w], 1); col[p] = sv.w;
        }
    }
}

// ---------------- fused MFMA GEMM: C[M,512] = A[M,K] @ Bt[512,K]^T + bias ----------------
// grid (4, M/128). 128x128 tile, BK=64. B (and bf16-A) via global_load_lds (m97).
// Epilogue: acc -> padded LDS tile -> coalesced dwordx4 stores.
template <bool AF32>
__global__ __launch_bounds__(256) void k_gemm(const void* __restrict__ Av,
                                              const bf16* __restrict__ Bt,
                                              const float* __restrict__ biasL,
                                              const float* __restrict__ biasR,
                                              bf16* __restrict__ C,
                                              int M, int K) {
    __shared__ bf16 smem[16896];      // staging: As=smem[0:8192), Bs=smem[8192:16384)
    bf16* As = smem;                  // epilogue: 128x132 padded output tile
    bf16* Bs = smem + 8192;
    const int tid  = threadIdx.x;
    const int wave = tid >> 6;
    const int lane = tid & 63;
    const int quad = lane >> 4;
    const int l16  = lane & 15;
    const int m0 = blockIdx.y * 128;
    const int n0 = blockIdx.x * 128;
    const int wm = (wave & 1) * 64;
    const int wn = (wave >> 1) * 64;

    floatx4 acc[4][4] = {};

    for (int k0 = 0; k0 < K; k0 += 64) {
        #pragma unroll
        for (int i = 0; i < 4; i++) {
            if (AF32) {
                const float* A = (const float*)Av;
                int flat = (i * 256 + tid) * 8;
                int row  = flat >> 6;
                int colk = flat & 63;
                const float* ap = A + (size_t)(m0 + row) * K + k0 + colk;
                bf16 tmp[8];
                #pragma unroll
                for (int q = 0; q < 8; q++) tmp[q] = f2b(ap[q]);
                *(short8*)&As[row * 64 + colk] = *(const short8*)tmp;
            } else {
                const bf16* A = (const bf16*)Av;
                int chunk = i * 4 + wave;
                int foff  = (chunk * 64 + lane) * 16;
                int row   = foff >> 7;
                int cole  = (foff & 127) >> 1;
                GLD_LDS16(A + (size_t)(m0 + row) * K + k0 + cole,
                          (char*)As + chunk * 1024 + lane * 16);
            }
            {
                int chunk = i * 4 + wave;
                int foff  = (chunk * 64 + lane) * 16;
                int row   = foff >> 7;
                int cole  = (foff & 127) >> 1;
                GLD_LDS16(Bt + (size_t)(n0 + row) * K + k0 + cole,
                          (char*)Bs + chunk * 1024 + lane * 16);
            }
        }
        __syncthreads();
        #pragma unroll
        for (int ks = 0; ks < 2; ks++) {
            short8 af[4], bfr[4];
            #pragma unroll
            for (int i = 0; i < 4; i++) {
                af[i]  = *(const short8*)&As[(wm + i * 16 + l16) * 64 + ks * 32 + quad * 8];
                bfr[i] = *(const short8*)&Bs[(wn + i * 16 + l16) * 64 + ks * 32 + quad * 8];
            }
            #pragma unroll
            for (int i = 0; i < 4; i++)
                #pragma unroll
                for (int j = 0; j < 4; j++)
                    acc[i][j] = __builtin_amdgcn_mfma_f32_16x16x32_bf16(af[i], bfr[j], acc[i][j], 0, 0, 0);
        }
        __syncthreads();
    }

    // C/D layout: col = lane&15, row = quad*4 + reg  [verified m89/m91]
    #pragma unroll
    for (int j = 0; j < 4; j++) {
        int lcol = wn + j * 16 + l16;
        int gcol = n0 + lcol;
        float bv = (gcol < 256) ? biasL[gcol] : biasR[gcol - 256];
        #pragma unroll
        for (int i = 0; i < 4; i++) {
            #pragma unroll
            for (int r = 0; r < 4; r++) {
                int lrow = wm + i * 16 + quad * 4 + r;
                smem[lrow * 132 + lcol] = f2b(acc[i][j][r] + bv);
            }
        }
    }
    __syncthreads();
    {
        int rl = tid >> 4;
        int cs = (tid & 15) * 8;
        #pragma unroll
        for (int p = 0; p < 8; p++) {
            int row = p * 16 + rl;
            short8 v = *(const short8*)&smem[row * 132 + cs];
            *(short8*)(C + (size_t)(m0 + row) * 512 + n0 + cs) = v;
        }
    }
}

// ---------------- GATv2 aggregation: half-wave per edge, 8 ch/lane (R9 structure) ----------------
__global__ __launch_bounds__(256) void k_agg(const bf16* __restrict__ xlr,
                                             const float* __restrict__ att,
                                             const int* __restrict__ row_ptr,
                                             const int* __restrict__ col,
                                             const float* __restrict__ bias,
                                             bf16* __restrict__ out, int do_gelu) {
    int wave = threadIdx.x >> 6, lane = threadIdx.x & 63;
    int i = blockIdx.x * 4 + wave;
    int hl = lane & 31;
    int half = lane >> 5;
    unsigned f = (hl >> 3) * 64 + (hl & 7) * 8;

    float att6[8], att4[8], xr_v[8];
    {
        floatx4 a0 = *(const floatx4*)(att + f);
        floatx4 a1 = *(const floatx4*)(att + f + 4);
        #pragma unroll
        for (int j = 0; j < 4; j++) {
            att6[j]     = 0.6f * a0[j]; att4[j]     = 0.4f * a0[j];
            att6[4 + j] = 0.6f * a1[j]; att4[4 + j] = 0.4f * a1[j];
        }
        bf16 t[8];
        *(short8*)t = *(const short8*)(xlr + ((unsigned)i * 512u + 256u + f));
        #pragma unroll
        for (int j = 0; j < 8; j++) xr_v[j] = b2f(t[j]);
    }

    int e0 = row_ptr[i], e1 = row_ptr[i + 1];
    int total = 1 + (e1 - e0);   // self + in-edges

    int src_c = i;
    if (half == 1 && total > 1) src_c = col[e0];
    bf16 g_cur[8];
    *(short8*)g_cur = *(const short8*)(xlr + ((unsigned)src_c * 512u + f));
    int t1 = 2 + half;
    int src_n = (t1 < total) ? col[e0 + t1 - 1] : i;

    float s = 0.f, acc[8] = {};

    for (int base = 0; base < total; base += 2) {
        bf16 g_nxt[8];
        *(short8*)g_nxt = *(const short8*)(xlr + ((unsigned)src_n * 512u + f));
        int t2 = base + 4 + half;
        int src_n2 = (t2 < total) ? col[e0 + t2 - 1] : i;
        bool valid = (base + half) < total;
        float xv[8], l = 0.f;
        #pragma unroll
        for (int j = 0; j < 8; j++) {
            xv[j] = b2f(g_cur[j]);
            float u = xv[j] + xr_v[j];
            l = fmaf(u, att6[j], fmaf(fabsf(u), att4[j], l));
        }
        l += __shfl_xor(l, 1, 8);
        l += __shfl_xor(l, 2, 8);
        l += __shfl_xor(l, 4, 8);
        float p = valid ? __expf(l) : 0.f;
        s += p;
        #pragma unroll
        for (int j = 0; j < 8; j++) acc[j] = fmaf(p, xv[j], acc[j]);
        #pragma unroll
        for (int j = 0; j < 8; j++) g_cur[j] = g_nxt[j];
        src_n = src_n2;
    }

    s += __shfl_xor(s, 32, 64);
    #pragma unroll
    for (int j = 0; j < 8; j++) acc[j] += __shfl_xor(acc[j], 32, 64);

    if (half == 0) {
        float inv = 1.0f / (s + 1e-16f);
        bf16 ov[8];
        #pragma unroll
        for (int j = 0; j < 8; j++) {
            float v = acc[j] * inv + bias[f + j];
            if (do_gelu) v = gelu_f(v);
            ov[j] = f2b(v);
        }
        *(short8*)(out + ((unsigned)i * 256u + f)) = *(const short8*)ov;
    }
}

// ---------------- shared head-layer body (block = one (graph, 64-col chunk)) ----------------
__device__ __forceinline__ void head_body(const bf16* __restrict__ inB,
                                          const float* __restrict__ inF,
                                          const float* __restrict__ W,
                                          const float* __restrict__ bias,
                                          float* __restrict__ out,
                                          int K, int N, long long row_stride, int act,
                                          int g, int chunk, float* zin, float* red) {
    int t = threadIdx.x;
    int nc = t & 63;
    int kq = t >> 6;
    int n = chunk * 64 + nc;
    for (int k = t; k < K; k += 256)
        zin[k] = inB ? b2f(inB[(size_t)g * row_stride + k])
                     : inF[(size_t)g * row_stride + k];
    __syncthreads();
    const int klen = K >> 2;
    const int kb = kq * klen;
    float acc = 0.f;
    #pragma unroll 8
    for (int k = 0; k < klen; k++)
        acc = fmaf(zin[kb + k], W[(size_t)(kb + k) * N + n], acc);
    red[t] = acc;
    __syncthreads();
    if (kq == 0) {
        float v = red[nc] + red[nc + 64] + red[nc + 128] + red[nc + 192] + bias[n];
        if (act) v = gelu_f(v);
        out[(size_t)g * N + n] = v;
    }
}

// ---------------- cooperative tail: pool1+lin1 | pool2+lin2 | fin ----------------
// 1024 blocks x 256 threads, low VGPR/LDS -> 4 blocks/CU co-residency guaranteed.
__global__ __launch_bounds__(256) void k_tail(const bf16* __restrict__ hb,
                                              float* __restrict__ part,
                                              const float* __restrict__ lin1w,
                                              const float* __restrict__ lin1b,
                                              float* __restrict__ t1,
                                              const float* __restrict__ lin2w,
                                              const float* __restrict__ lin2b,
                                              float* __restrict__ t2,
                                              const float* __restrict__ finw,
                                              const float* __restrict__ finb,
                                              float* __restrict__ outp,
                                              float* __restrict__ outPool, int PG) {
    cg::grid_group grid = cg::this_grid();
    __shared__ float zin[1024];
    __shared__ float red[256];
    int b = blockIdx.x, t = threadIdx.x;

    // phase 1: pool partials (blocks 0..511) + lin1 (all 1024 blocks)
    if (b < 512) {
        int g = b >> 3, p = b & 7, c = t;
        int rows_per = PG / 8;
        const bf16* base = hb + ((size_t)g * PG + (size_t)p * rows_per) * 256;
        float acc = 0.f;
        for (int r = 0; r < rows_per; r++) acc += b2f(base[(size_t)r * 256 + c]);
        part[((size_t)g * 8 + p) * 256 + c] = acc;
    }
    head_body(hb, nullptr, lin1w, lin1b, t1, 256, 1024,
              (long long)PG * 256, 1, b >> 4, b & 15, zin, red);
    grid.sync();

    // phase 2: pool final (blocks 0..63) + lin2 (blocks 64..319)
    if (b < 64) {
        int g = b, c = t;
        float acc = 0.f;
        for (int p = 0; p < 8; p++) acc += part[((size_t)g * 8 + p) * 256 + c];
        outPool[g * 256 + c] = acc / (float)PG;
    } else if (b < 320) {
        int u = b - 64;
        head_body(nullptr, t1, lin2w, lin2b, t2, 1024, 256,
                  1024, 0, u >> 2, u & 3, zin, red);
    }
    grid.sync();

    // phase 3: fin (blocks 0..511)
    if (b < 512) {
        head_body(nullptr, t2, finw, finb, outp, 256, 512,
                  256, 0, b >> 3, b & 7, zin, red);
    }
}

extern "C" void kernel_launch(void* const* d_in, const int* in_sizes, int n_in,
                              void* d_out, int out_size, void* d_ws, size_t ws_size,
                              hipStream_t stream) {
    const float* x     = (const float*)d_in[0];
    const int*   ei    = (const int*)d_in[1];
    const float* w1_l  = (const float*)d_in[4];
    const float* b1_l  = (const float*)d_in[5];
    const float* w1_r  = (const float*)d_in[6];
    const float* b1_r  = (const float*)d_in[7];
    const float* att1  = (const float*)d_in[8];
    const float* bias1 = (const float*)d_in[9];
    const float* w2_l  = (const float*)d_in[10];
    const float* b2_l  = (const float*)d_in[11];
    const float* w2_r  = (const float*)d_in[12];
    const float* b2_r  = (const float*)d_in[13];
    const float* att2  = (const float*)d_in[14];
    const float* bias2 = (const float*)d_in[15];
    const float* lin1w = (const float*)d_in[16];
    const float* lin1b = (const float*)d_in[17];
    const float* lin2w = (const float*)d_in[18];
    const float* lin2b = (const float*)d_in[19];
    const float* finw  = (const float*)d_in[20];
    const float* finb  = (const float*)d_in[21];

    const int N  = in_sizes[0] / 256;   // 32768
    int E        = in_sizes[1] / 2;     // 524288
    const int NG = 64;
    int PG       = N / NG;              // 512

    // workspace layout (~52.5 MiB)
    char* ws = (char*)d_ws;
    size_t off = 0;
    bf16* xlr = (bf16*)(ws + off); off += (size_t)N * 512 * 2;    // 32 MiB [xl|xr]
    bf16* hb  = (bf16*)(ws + off); off += (size_t)N * 256 * 2;    // 16 MiB (h1 then h2)
    bf16* wt  = (bf16*)(ws + off); off += 2 * 512 * 256 * 2;      // 512 KiB both layers' Wt
    int* row_ptr = (int*)(ws + off); off += (size_t)(N + 4) * 4;
    int* cnt     = (int*)(ws + off); off += (size_t)N * 4;
    int* fill    = (int*)(ws + off); off += (size_t)N * 4;
    int* col     = (int*)(ws + off); off += (size_t)E * 4;
    int* btot    = (int*)(ws + off); off += 512 * 4;
    float* pws   = (float*)(ws + off); off += (size_t)NG * 8 * 256 * 4;  // pool partials
    float* t1    = (float*)(ws + off); off += (size_t)NG * 1024 * 4;
    float* t2    = (float*)(ws + off); off += (size_t)NG * 256 * 4;

    const int* srcv = ei;
    const int* dstv = ei + E;
    float* outp    = (float*)d_out;
    float* outPool = outp + 64 * 512;

    // --- cooperative CSR build + weight transposes (one dispatch) ---
    {
        void* args[] = {(void*)&dstv, (void*)&srcv, (void*)&cnt, (void*)&row_ptr,
                        (void*)&fill, (void*)&col, (void*)&E,
                        (void*)&w1_l, (void*)&w1_r, (void*)&w2_l, (void*)&w2_r,
                        (void*)&wt, (void*)&btot};
        hipLaunchCooperativeKernel((void*)k_csr, dim3(512), dim3(256), args, 0, stream);
    }

    dim3 gg(4, N / 128);   // fused L/R: N-dim 512
    // --- layer 1 (A = x fp32) ---
    k_gemm<true><<<gg, 256, 0, stream>>>(x, wt, b1_l, b1_r, xlr, N, 256);
    k_agg<<<N / 4, 256, 0, stream>>>(xlr, att1, row_ptr, col, bias1, hb, 1);  // + GELU

    // --- layer 2 (A = h1 bf16) ---
    k_gemm<false><<<gg, 256, 0, stream>>>(hb, wt + 512 * 256, b2_l, b2_r, xlr, N, 256);
    k_agg<<<N / 4, 256, 0, stream>>>(xlr, att2, row_ptr, col, bias2, hb, 0);  // h2

    // --- cooperative tail: pool + 3-layer MLP head (one dispatch) ---
    {
        void* args[] = {(void*)&hb, (void*)&pws, (void*)&lin1w, (void*)&lin1b,
                        (void*)&t1, (void*)&lin2w, (void*)&lin2b, (void*)&t2,
                        (void*)&finw, (void*)&finb, (void*)&outp, (void*)&outPool,
                        (void*)&PG};
        hipLaunchCooperativeKernel((void*)k_tail, dim3(1024), dim3(256), args, 0, stream);
    }
}

// Round 13
// 361.995 us; speedup vs baseline: 2.2910x; 2.2910x over previous
//
#include <hip/hip_runtime.h>
#include <hip/hip_bf16.h>
#include <stdint.h>

typedef __attribute__((ext_vector_type(8))) short short8;
typedef __attribute__((ext_vector_type(4))) short short4v;
typedef __attribute__((ext_vector_type(4))) float floatx4;
typedef __hip_bfloat16 bf16;

__device__ __forceinline__ float b2f(bf16 v) { return __bfloat162float(v); }
__device__ __forceinline__ bf16 f2b(float v) { return __float2bfloat16(v); }
__device__ __forceinline__ float gelu_f(float v) {
    return 0.5f * v * (1.0f + erff(v * 0.70710678118654752f));
}

#define GLD_LDS16(gptr, lptr) \
  __builtin_amdgcn_global_load_lds((const __attribute__((address_space(1))) void*)(gptr), \
                                   (__attribute__((address_space(3))) void*)(lptr), 16, 0, 0)

// NOTE (R12 lesson): hipLaunchCooperativeKernel grid.sync() costs ~60us each on this
// stack under graph capture -- ~10x a dispatch gap. Never fuse via grid.sync here.

// ---------------- fused: CSR count (blocks 0..511) + weight transposes (512..1535) ----------------
// Wt[layer][512][256] bf16: rows 0..255 = W_l columns, 256..511 = W_r columns
__global__ void k_count_tr(const int* __restrict__ dst, int* __restrict__ cnt, int E,
                           const float* __restrict__ Wl1, const float* __restrict__ Wr1,
                           const float* __restrict__ Wl2, const float* __restrict__ Wr2,
                           bf16* __restrict__ Wt) {
    int bx = blockIdx.x;
    if (bx < 512) {
        int g = bx * 256 + threadIdx.x;
        if (g * 4 < E) {
            int4 d = ((const int4*)dst)[g];
            atomicAdd(&cnt[d.x], 1);
            atomicAdd(&cnt[d.y], 1);
            atomicAdd(&cnt[d.z], 1);
            atomicAdd(&cnt[d.w], 1);
        }
    } else {
        int b = bx - 512;
        int r = b & 255, half = (b >> 8) & 1, layer = b >> 9;
        int c = threadIdx.x;
        const float* W = layer ? (half ? Wr2 : Wl2) : (half ? Wr1 : Wl1);
        Wt[(size_t)(layer * 512 + half * 256 + c) * 256 + r] = f2b(W[r * 256 + c]);
    }
}

// n must be 32768: 1024 threads x 32 elements each (int4 loads)
__global__ __launch_bounds__(1024) void k_scan(const int* __restrict__ cnt,
                                               int* __restrict__ row_ptr,
                                               int* __restrict__ fill, int n) {
    __shared__ int sdata[1024];
    int t = threadIdx.x;
    int base = t * 32;
    int local[32];
    const int4* c4 = (const int4*)(cnt + base);
    int vals[32];
    #pragma unroll
    for (int q = 0; q < 8; q++) {
        int4 v = c4[q];
        vals[q * 4 + 0] = v.x; vals[q * 4 + 1] = v.y;
        vals[q * 4 + 2] = v.z; vals[q * 4 + 3] = v.w;
    }
    int sum = 0;
    #pragma unroll
    for (int k = 0; k < 32; k++) { local[k] = sum; sum += vals[k]; }
    sdata[t] = sum;
    __syncthreads();
    for (int off = 1; off < 1024; off <<= 1) {
        int v = (t >= off) ? sdata[t - off] : 0;
        __syncthreads();
        sdata[t] += v;
        __syncthreads();
    }
    int excl = sdata[t] - sum;
    #pragma unroll
    for (int k = 0; k < 32; k++) {
        int v = excl + local[k];
        row_ptr[base + k] = v;
        fill[base + k] = v;
    }
    if (t == 1023) row_ptr[n] = excl + sum;
}

// ---------------- GEMM tile body: C[M,512] = A[M,K] @ Bt[512,K]^T + bias ----------------
// 128x128 tile, BK=64. B (and bf16-A) via global_load_lds (m97).
// Epilogue: acc -> padded LDS tile -> coalesced dwordx4 stores.
template <bool AF32>
__device__ __forceinline__ void gemm_body(const void* __restrict__ Av,
                                          const bf16* __restrict__ Bt,
                                          const float* __restrict__ biasL,
                                          const float* __restrict__ biasR,
                                          bf16* __restrict__ C,
                                          int K, int m0, int n0,
                                          bf16* __restrict__ smem) {
    bf16* As = smem;
    bf16* Bs = smem + 8192;
    const int tid  = threadIdx.x;
    const int wave = tid >> 6;
    const int lane = tid & 63;
    const int quad = lane >> 4;
    const int l16  = lane & 15;
    const int wm = (wave & 1) * 64;
    const int wn = (wave >> 1) * 64;

    floatx4 acc[4][4] = {};

    for (int k0 = 0; k0 < K; k0 += 64) {
        #pragma unroll
        for (int i = 0; i < 4; i++) {
            if (AF32) {
                const float* A = (const float*)Av;
                int flat = (i * 256 + tid) * 8;
                int row  = flat >> 6;
                int colk = flat & 63;
                const float* ap = A + (size_t)(m0 + row) * K + k0 + colk;
                bf16 tmp[8];
                #pragma unroll
                for (int q = 0; q < 8; q++) tmp[q] = f2b(ap[q]);
                *(short8*)&As[row * 64 + colk] = *(const short8*)tmp;
            } else {
                const bf16* A = (const bf16*)Av;
                int chunk = i * 4 + wave;
                int foff  = (chunk * 64 + lane) * 16;
                int row   = foff >> 7;
                int cole  = (foff & 127) >> 1;
                GLD_LDS16(A + (size_t)(m0 + row) * K + k0 + cole,
                          (char*)As + chunk * 1024 + lane * 16);
            }
            {
                int chunk = i * 4 + wave;
                int foff  = (chunk * 64 + lane) * 16;
                int row   = foff >> 7;
                int cole  = (foff & 127) >> 1;
                GLD_LDS16(Bt + (size_t)(n0 + row) * K + k0 + cole,
                          (char*)Bs + chunk * 1024 + lane * 16);
            }
        }
        __syncthreads();
        #pragma unroll
        for (int ks = 0; ks < 2; ks++) {
            short8 af[4], bfr[4];
            #pragma unroll
            for (int i = 0; i < 4; i++) {
                af[i]  = *(const short8*)&As[(wm + i * 16 + l16) * 64 + ks * 32 + quad * 8];
                bfr[i] = *(const short8*)&Bs[(wn + i * 16 + l16) * 64 + ks * 32 + quad * 8];
            }
            #pragma unroll
            for (int i = 0; i < 4; i++)
                #pragma unroll
                for (int j = 0; j < 4; j++)
                    acc[i][j] = __builtin_amdgcn_mfma_f32_16x16x32_bf16(af[i], bfr[j], acc[i][j], 0, 0, 0);
        }
        __syncthreads();
    }

    // C/D layout: col = lane&15, row = quad*4 + reg  [verified m89/m91]
    #pragma unroll
    for (int j = 0; j < 4; j++) {
        int lcol = wn + j * 16 + l16;
        int gcol = n0 + lcol;
        float bv = (gcol < 256) ? biasL[gcol] : biasR[gcol - 256];
        #pragma unroll
        for (int i = 0; i < 4; i++) {
            #pragma unroll
            for (int r = 0; r < 4; r++) {
                int lrow = wm + i * 16 + quad * 4 + r;
                smem[lrow * 132 + lcol] = f2b(acc[i][j][r] + bv);
            }
        }
    }
    __syncthreads();
    {
        int rl = tid >> 4;
        int cs = (tid & 15) * 8;
        #pragma unroll
        for (int p = 0; p < 8; p++) {
            int row = p * 16 + rl;
            short8 v = *(const short8*)&smem[row * 132 + cs];
            *(short8*)(C + (size_t)(m0 + row) * 512 + n0 + cs) = v;
        }
    }
}

// ---------------- union dispatch: scatter (blocks 0..511) + layer-1 GEMM (512..1535) ----------------
// Both depend only on k_scan's output; independent of each other; agg1 needs both.
__global__ __launch_bounds__(256) void k_scatter_gemm(const int* __restrict__ src,
                                                      const int* __restrict__ dst,
                                                      int* __restrict__ fill,
                                                      int* __restrict__ col, int E,
                                                      const float* __restrict__ A,
                                                      const bf16* __restrict__ Bt,
                                                      const float* __restrict__ biasL,
                                                      const float* __restrict__ biasR,
                                                      bf16* __restrict__ C, int K) {
    __shared__ bf16 smem[16896];
    int bx = blockIdx.x;
    if (bx < 512) {
        int g = bx * 256 + threadIdx.x;
        if (g * 4 < E) {
            int4 d = ((const int4*)dst)[g];
            int4 sv = ((const int4*)src)[g];
            int p;
            p = atomicAdd(&fill[d.x], 1); col[p] = sv.x;
            p = atomicAdd(&fill[d.y], 1); col[p] = sv.y;
            p = atomicAdd(&fill[d.z], 1); col[p] = sv.z;
            p = atomicAdd(&fill[d.w], 1); col[p] = sv.w;
        }
    } else {
        int b = bx - 512;
        int n0 = (b & 3) * 128;
        int m0 = (b >> 2) * 128;
        gemm_body<true>(A, Bt, biasL, biasR, C, K, m0, n0, smem);
    }
}

// ---------------- standalone GEMM (layer 2, bf16 A) ----------------
__global__ __launch_bounds__(256) void k_gemm2(const bf16* __restrict__ A,
                                               const bf16* __restrict__ Bt,
                                               const float* __restrict__ biasL,
                                               const float* __restrict__ biasR,
                                               bf16* __restrict__ C, int K) {
    __shared__ bf16 smem[16896];
    int n0 = blockIdx.x * 128;
    int m0 = blockIdx.y * 128;
    gemm_body<false>(A, Bt, biasL, biasR, C, K, m0, n0, smem);
}

// ---------------- GATv2 aggregation: half-wave per edge, 8 ch/lane (R9 structure) ----------------
// One wave per dst node. Lanes 0-31 = item a, 32-63 = item b of each pair.
// Within a half: 8 lanes per head (hl>>3), 8 channels per lane ((hl&7)*8).
// Item 0 = self-loop, items 1..deg = CSR edges. Max-free softmax (logits bounded),
// leaky folded into att (0.6u + 0.4|u|). 32-bit element offsets (SGPR-base addressing).
__global__ __launch_bounds__(256) void k_agg(const bf16* __restrict__ xlr,
                                             const float* __restrict__ att,
                                             const int* __restrict__ row_ptr,
                                             const int* __restrict__ col,
                                             const float* __restrict__ bias,
                                             bf16* __restrict__ out, int do_gelu) {
    int wave = threadIdx.x >> 6, lane = threadIdx.x & 63;
    int i = blockIdx.x * 4 + wave;
    int hl = lane & 31;
    int half = lane >> 5;
    unsigned f = (hl >> 3) * 64 + (hl & 7) * 8;

    float att6[8], att4[8], xr_v[8];
    {
        floatx4 a0 = *(const floatx4*)(att + f);
        floatx4 a1 = *(const floatx4*)(att + f + 4);
        #pragma unroll
        for (int j = 0; j < 4; j++) {
            att6[j]     = 0.6f * a0[j]; att4[j]     = 0.4f * a0[j];
            att6[4 + j] = 0.6f * a1[j]; att4[4 + j] = 0.4f * a1[j];
        }
        bf16 t[8];
        *(short8*)t = *(const short8*)(xlr + ((unsigned)i * 512u + 256u + f));
        #pragma unroll
        for (int j = 0; j < 8; j++) xr_v[j] = b2f(t[j]);
    }

    int e0 = row_ptr[i], e1 = row_ptr[i + 1];
    int total = 1 + (e1 - e0);   // self + in-edges

    int src_c = i;
    if (half == 1 && total > 1) src_c = col[e0];
    bf16 g_cur[8];
    *(short8*)g_cur = *(const short8*)(xlr + ((unsigned)src_c * 512u + f));
    int t1 = 2 + half;
    int src_n = (t1 < total) ? col[e0 + t1 - 1] : i;

    float s = 0.f, acc[8] = {};

    for (int base = 0; base < total; base += 2) {
        bf16 g_nxt[8];
        *(short8*)g_nxt = *(const short8*)(xlr + ((unsigned)src_n * 512u + f));
        int t2 = base + 4 + half;
        int src_n2 = (t2 < total) ? col[e0 + t2 - 1] : i;
        bool valid = (base + half) < total;
        float xv[8], l = 0.f;
        #pragma unroll
        for (int j = 0; j < 8; j++) {
            xv[j] = b2f(g_cur[j]);
            float u = xv[j] + xr_v[j];
            l = fmaf(u, att6[j], fmaf(fabsf(u), att4[j], l));
        }
        l += __shfl_xor(l, 1, 8);
        l += __shfl_xor(l, 2, 8);
        l += __shfl_xor(l, 4, 8);
        float p = valid ? __expf(l) : 0.f;
        s += p;
        #pragma unroll
        for (int j = 0; j < 8; j++) acc[j] = fmaf(p, xv[j], acc[j]);
        #pragma unroll
        for (int j = 0; j < 8; j++) g_cur[j] = g_nxt[j];
        src_n = src_n2;
    }

    s += __shfl_xor(s, 32, 64);
    #pragma unroll
    for (int j = 0; j < 8; j++) acc[j] += __shfl_xor(acc[j], 32, 64);

    if (half == 0) {
        float inv = 1.0f / (s + 1e-16f);
        bf16 ov[8];
        #pragma unroll
        for (int j = 0; j < 8; j++) {
            float v = acc[j] * inv + bias[f + j];
            if (do_gelu) v = gelu_f(v);
            ov[j] = f2b(v);
        }
        *(short8*)(out + ((unsigned)i * 256u + f)) = *(const short8*)ov;
    }
}

// ---------------- shared head-layer body (block = one (graph, 64-col chunk)) ----------------
__device__ __forceinline__ void head_body(const bf16* __restrict__ inB,
                                          const float* __restrict__ inF,
                                          const float* __restrict__ W,
                                          const float* __restrict__ bias,
                                          float* __restrict__ out,
                                          int K, int N, long long row_stride, int act,
                                          int g, int chunk, float* zin, float* red) {
    int t = threadIdx.x;
    int nc = t & 63;
    int kq = t >> 6;
    int n = chunk * 64 + nc;
    for (int k = t; k < K; k += 256)
        zin[k] = inB ? b2f(inB[(size_t)g * row_stride + k])
                     : inF[(size_t)g * row_stride + k];
    __syncthreads();
    const int klen = K >> 2;
    const int kb = kq * klen;
    float acc = 0.f;
    #pragma unroll 8
    for (int k = 0; k < klen; k++)
        acc = fmaf(zin[kb + k], W[(size_t)(kb + k) * N + n], acc);
    red[t] = acc;
    __syncthreads();
    if (kq == 0) {
        float v = red[nc] + red[nc + 64] + red[nc + 128] + red[nc + 192] + bias[n];
        if (act) v = gelu_f(v);
        out[(size_t)g * N + n] = v;
    }
}

// ---------------- fused: pool stage 1 (blocks 0..511) + head lin1 (512..1535) ----------------
__global__ __launch_bounds__(256) void k_pe1(const bf16* __restrict__ hb,
                                             float* __restrict__ part,
                                             const float* __restrict__ lin1w,
                                             const float* __restrict__ lin1b,
                                             float* __restrict__ t1, int PG) {
    __shared__ float zin[256];
    __shared__ float red[256];
    int bx = blockIdx.x;
    if (bx < 512) {
        int g = bx >> 3, p = bx & 7, c = threadIdx.x;
        int rows_per = PG / 8;
        const bf16* base = hb + ((size_t)g * PG + (size_t)p * rows_per) * 256;
        float acc = 0.f;
        for (int r = 0; r < rows_per; r++) acc += b2f(base[(size_t)r * 256 + c]);
        part[((size_t)g * 8 + p) * 256 + c] = acc;
    } else {
        int b = bx - 512;
        head_body(hb, nullptr, lin1w, lin1b, t1, 256, 1024,
                  (long long)PG * 256, 1, b >> 4, b & 15, zin, red);
    }
}

// ---------------- fused: pool stage 2 (blocks 0..63) + head lin2 (64..319) ----------------
__global__ __launch_bounds__(256) void k_pe2(const float* __restrict__ part,
                                             float* __restrict__ outPool, int PG,
                                             const float* __restrict__ t1,
                                             const float* __restrict__ lin2w,
                                             const float* __restrict__ lin2b,
                                             float* __restrict__ t2) {
    __shared__ float zin[1024];
    __shared__ float red[256];
    int bx = blockIdx.x;
    if (bx < 64) {
        int g = bx, c = threadIdx.x;
        float acc = 0.f;
        for (int p = 0; p < 8; p++) acc += part[((size_t)g * 8 + p) * 256 + c];
        outPool[g * 256 + c] = acc / (float)PG;
    } else {
        int b = bx - 64;
        head_body(nullptr, t1, lin2w, lin2b, t2, 1024, 256,
                  1024, 0, b >> 2, b & 3, zin, red);
    }
}

// ---------------- final head layer ----------------
__global__ __launch_bounds__(256) void k_fin(const float* __restrict__ t2,
                                             const float* __restrict__ finw,
                                             const float* __restrict__ finb,
                                             float* __restrict__ out) {
    __shared__ float zin[256];
    __shared__ float red[256];
    head_body(nullptr, t2, finw, finb, out, 256, 512,
              256, 0, blockIdx.x, blockIdx.y, zin, red);
}

extern "C" void kernel_launch(void* const* d_in, const int* in_sizes, int n_in,
                              void* d_out, int out_size, void* d_ws, size_t ws_size,
                              hipStream_t stream) {
    const float* x     = (const float*)d_in[0];
    const int*   ei    = (const int*)d_in[1];
    const float* w1_l  = (const float*)d_in[4];
    const float* b1_l  = (const float*)d_in[5];
    const float* w1_r  = (const float*)d_in[6];
    const float* b1_r  = (const float*)d_in[7];
    const float* att1  = (const float*)d_in[8];
    const float* bias1 = (const float*)d_in[9];
    const float* w2_l  = (const float*)d_in[10];
    const float* b2_l  = (const float*)d_in[11];
    const float* w2_r  = (const float*)d_in[12];
    const float* b2_r  = (const float*)d_in[13];
    const float* att2  = (const float*)d_in[14];
    const float* bias2 = (const float*)d_in[15];
    const float* lin1w = (const float*)d_in[16];
    const float* lin1b = (const float*)d_in[17];
    const float* lin2w = (const float*)d_in[18];
    const float* lin2b = (const float*)d_in[19];
    const float* finw  = (const float*)d_in[20];
    const float* finb  = (const float*)d_in[21];

    const int N  = in_sizes[0] / 256;   // 32768
    const int E  = in_sizes[1] / 2;     // 524288
    const int NG = 64;
    const int PG = N / NG;              // 512

    // workspace layout (~52.5 MiB)
    char* ws = (char*)d_ws;
    size_t off = 0;
    bf16* xlr = (bf16*)(ws + off); off += (size_t)N * 512 * 2;    // 32 MiB [xl|xr]
    bf16* hb  = (bf16*)(ws + off); off += (size_t)N * 256 * 2;    // 16 MiB (h1 then h2)
    bf16* wt  = (bf16*)(ws + off); off += 2 * 512 * 256 * 2;      // 512 KiB both layers' Wt
    int* row_ptr = (int*)(ws + off); off += (size_t)(N + 4) * 4;
    int* cnt     = (int*)(ws + off); off += (size_t)N * 4;
    int* fill    = (int*)(ws + off); off += (size_t)N * 4;
    int* col     = (int*)(ws + off); off += (size_t)E * 4;
    float* pws   = (float*)(ws + off); off += (size_t)NG * 8 * 256 * 4;  // pool partials
    float* t1    = (float*)(ws + off); off += (size_t)NG * 1024 * 4;
    float* t2    = (float*)(ws + off); off += (size_t)NG * 256 * 4;

    const int* srcv = ei;
    const int* dstv = ei + E;

    // --- CSR count + weight transposes (one launch) ---
    hipMemsetAsync(cnt, 0, (size_t)N * 4, stream);
    k_count_tr<<<512 + 1024, 256, 0, stream>>>(dstv, cnt, E,
                                               w1_l, w1_r, w2_l, w2_r, wt);
    k_scan<<<1, 1024, 0, stream>>>(cnt, row_ptr, fill, N);

    // --- scatter + layer-1 GEMM (one union launch; both ready after scan) ---
    k_scatter_gemm<<<512 + 1024, 256, 0, stream>>>(srcv, dstv, fill, col, E,
                                                   x, wt, b1_l, b1_r, xlr, 256);
    k_agg<<<N / 4, 256, 0, stream>>>(xlr, att1, row_ptr, col, bias1, hb, 1);  // + GELU

    // --- layer 2 (A = h1 bf16) ---
    dim3 gg(4, N / 128);
    k_gemm2<<<gg, 256, 0, stream>>>(hb, wt + 512 * 256, b2_l, b2_r, xlr, 256);
    k_agg<<<N / 4, 256, 0, stream>>>(xlr, att2, row_ptr, col, bias2, hb, 0);  // h2

    float* outp = (float*)d_out;
    // --- pool1 + head lin1 (one launch) ---
    k_pe1<<<512 + 1024, 256, 0, stream>>>(hb, pws, lin1w, lin1b, t1, PG);
    // --- pool2 (-> d_out[64*512..]) + head lin2 (one launch) ---
    k_pe2<<<64 + 256, 256, 0, stream>>>(pws, outp + 64 * 512, PG, t1, lin2w, lin2b, t2);
    // --- final head layer -> d_out[0..64*512) ---
    dim3 gf(NG, 512 / 64);
    k_fin<<<gf, 256, 0, stream>>>(t2, finw, finb, outp);
}

// Round 14
// 350.224 us; speedup vs baseline: 2.3680x; 1.0336x over previous
//
#include <hip/hip_runtime.h>
#include <hip/hip_bf16.h>
#include <stdint.h>

typedef __attribute__((ext_vector_type(8))) short short8;
typedef __attribute__((ext_vector_type(4))) short short4v;
typedef __attribute__((ext_vector_type(4))) float floatx4;
typedef __hip_bfloat16 bf16;

__device__ __forceinline__ float b2f(bf16 v) { return __bfloat162float(v); }
__device__ __forceinline__ bf16 f2b(float v) { return __float2bfloat16(v); }
__device__ __forceinline__ float gelu_f(float v) {
    return 0.5f * v * (1.0f + erff(v * 0.70710678118654752f));
}

#define GLD_LDS16(gptr, lptr) \
  __builtin_amdgcn_global_load_lds((const __attribute__((address_space(1))) void*)(gptr), \
                                   (__attribute__((address_space(3))) void*)(lptr), 16, 0, 0)

// NOTE (R12 lesson): hipLaunchCooperativeKernel grid.sync() costs ~60us each on this
// stack under graph capture -- ~10x a dispatch gap. Never fuse via grid.sync here.
// NOTE (R13 lesson): epilogue LDS tile stride must be 16B-aligned (132 elems = 264B
// broke ds_read_b128 alignment -> 3.1M conflict cycles). Use 136 elems = 272B.

// ---------------- fused: CSR count (blocks 0..511) + weight transposes (512..1535) ----------------
// Wt[layer][512][256] bf16: rows 0..255 = W_l columns, 256..511 = W_r columns
__global__ void k_count_tr(const int* __restrict__ dst, int* __restrict__ cnt, int E,
                           const float* __restrict__ Wl1, const float* __restrict__ Wr1,
                           const float* __restrict__ Wl2, const float* __restrict__ Wr2,
                           bf16* __restrict__ Wt) {
    int bx = blockIdx.x;
    if (bx < 512) {
        int g = bx * 256 + threadIdx.x;
        if (g * 4 < E) {
            int4 d = ((const int4*)dst)[g];
            atomicAdd(&cnt[d.x], 1);
            atomicAdd(&cnt[d.y], 1);
            atomicAdd(&cnt[d.z], 1);
            atomicAdd(&cnt[d.w], 1);
        }
    } else {
        int b = bx - 512;
        int r = b & 255, half = (b >> 8) & 1, layer = b >> 9;
        int c = threadIdx.x;
        const float* W = layer ? (half ? Wr2 : Wl2) : (half ? Wr1 : Wl1);
        Wt[(size_t)(layer * 512 + half * 256 + c) * 256 + r] = f2b(W[r * 256 + c]);
    }
}

// n must be 32768: 1024 threads x 32 elements each (int4 loads)
__global__ __launch_bounds__(1024) void k_scan(const int* __restrict__ cnt,
                                               int* __restrict__ row_ptr,
                                               int* __restrict__ fill, int n) {
    __shared__ int sdata[1024];
    int t = threadIdx.x;
    int base = t * 32;
    int local[32];
    const int4* c4 = (const int4*)(cnt + base);
    int vals[32];
    #pragma unroll
    for (int q = 0; q < 8; q++) {
        int4 v = c4[q];
        vals[q * 4 + 0] = v.x; vals[q * 4 + 1] = v.y;
        vals[q * 4 + 2] = v.z; vals[q * 4 + 3] = v.w;
    }
    int sum = 0;
    #pragma unroll
    for (int k = 0; k < 32; k++) { local[k] = sum; sum += vals[k]; }
    sdata[t] = sum;
    __syncthreads();
    for (int off = 1; off < 1024; off <<= 1) {
        int v = (t >= off) ? sdata[t - off] : 0;
        __syncthreads();
        sdata[t] += v;
        __syncthreads();
    }
    int excl = sdata[t] - sum;
    #pragma unroll
    for (int k = 0; k < 32; k++) {
        int v = excl + local[k];
        row_ptr[base + k] = v;
        fill[base + k] = v;
    }
    if (t == 1023) row_ptr[n] = excl + sum;
}

// ---------------- GEMM tile body: C[M,512] = A[M,K] @ Bt[512,K]^T + bias ----------------
// 128x128 tile, BK=64. B (and bf16-A) via global_load_lds (m97).
// Epilogue: acc -> LDS tile (stride 136, 16B-aligned rows) -> coalesced dwordx4 stores.
template <bool AF32>
__device__ __forceinline__ void gemm_body(const void* __restrict__ Av,
                                          const bf16* __restrict__ Bt,
                                          const float* __restrict__ biasL,
                                          const float* __restrict__ biasR,
                                          bf16* __restrict__ C,
                                          int K, int m0, int n0,
                                          bf16* __restrict__ smem) {
    bf16* As = smem;
    bf16* Bs = smem + 8192;
    const int tid  = threadIdx.x;
    const int wave = tid >> 6;
    const int lane = tid & 63;
    const int quad = lane >> 4;
    const int l16  = lane & 15;
    const int wm = (wave & 1) * 64;
    const int wn = (wave >> 1) * 64;

    floatx4 acc[4][4] = {};

    for (int k0 = 0; k0 < K; k0 += 64) {
        #pragma unroll
        for (int i = 0; i < 4; i++) {
            if (AF32) {
                const float* A = (const float*)Av;
                int flat = (i * 256 + tid) * 8;
                int row  = flat >> 6;
                int colk = flat & 63;
                const float* ap = A + (size_t)(m0 + row) * K + k0 + colk;
                bf16 tmp[8];
                #pragma unroll
                for (int q = 0; q < 8; q++) tmp[q] = f2b(ap[q]);
                *(short8*)&As[row * 64 + colk] = *(const short8*)tmp;
            } else {
                const bf16* A = (const bf16*)Av;
                int chunk = i * 4 + wave;
                int foff  = (chunk * 64 + lane) * 16;
                int row   = foff >> 7;
                int cole  = (foff & 127) >> 1;
                GLD_LDS16(A + (size_t)(m0 + row) * K + k0 + cole,
                          (char*)As + chunk * 1024 + lane * 16);
            }
            {
                int chunk = i * 4 + wave;
                int foff  = (chunk * 64 + lane) * 16;
                int row   = foff >> 7;
                int cole  = (foff & 127) >> 1;
                GLD_LDS16(Bt + (size_t)(n0 + row) * K + k0 + cole,
                          (char*)Bs + chunk * 1024 + lane * 16);
            }
        }
        __syncthreads();
        #pragma unroll
        for (int ks = 0; ks < 2; ks++) {
            short8 af[4], bfr[4];
            #pragma unroll
            for (int i = 0; i < 4; i++) {
                af[i]  = *(const short8*)&As[(wm + i * 16 + l16) * 64 + ks * 32 + quad * 8];
                bfr[i] = *(const short8*)&Bs[(wn + i * 16 + l16) * 64 + ks * 32 + quad * 8];
            }
            #pragma unroll
            for (int i = 0; i < 4; i++)
                #pragma unroll
                for (int j = 0; j < 4; j++)
                    acc[i][j] = __builtin_amdgcn_mfma_f32_16x16x32_bf16(af[i], bfr[j], acc[i][j], 0, 0, 0);
        }
        __syncthreads();
    }

    // C/D layout: col = lane&15, row = quad*4 + reg  [verified m89/m91]
    #pragma unroll
    for (int j = 0; j < 4; j++) {
        int lcol = wn + j * 16 + l16;
        int gcol = n0 + lcol;
        float bv = (gcol < 256) ? biasL[gcol] : biasR[gcol - 256];
        #pragma unroll
        for (int i = 0; i < 4; i++) {
            #pragma unroll
            for (int r = 0; r < 4; r++) {
                int lrow = wm + i * 16 + quad * 4 + r;
                smem[lrow * 136 + lcol] = f2b(acc[i][j][r] + bv);
            }
        }
    }
    __syncthreads();
    {
        int rl = tid >> 4;
        int cs = (tid & 15) * 8;
        #pragma unroll
        for (int p = 0; p < 8; p++) {
            int row = p * 16 + rl;
            short8 v = *(const short8*)&smem[row * 136 + cs];
            *(short8*)(C + (size_t)(m0 + row) * 512 + n0 + cs) = v;
        }
    }
}

// ---------------- union dispatch: scatter + layer-1 GEMM, roles INTERLEAVED ----------------
// bx%3==2 -> scatter (512 blocks), else GEMM (1024 blocks). Interleaving keeps both
// kinds co-resident per CU: latency-bound scatter overlaps MFMA-bound GEMM (m114).
__global__ __launch_bounds__(256) void k_scatter_gemm(const int* __restrict__ src,
                                                      const int* __restrict__ dst,
                                                      int* __restrict__ fill,
                                                      int* __restrict__ col, int E,
                                                      const float* __restrict__ A,
                                                      const bf16* __restrict__ Bt,
                                                      const float* __restrict__ biasL,
                                                      const float* __restrict__ biasR,
                                                      bf16* __restrict__ C, int K) {
    __shared__ bf16 smem[17408];
    int bx = blockIdx.x;
    int rem = bx % 3;
    if (rem == 2) {
        int g = (bx / 3) * 256 + threadIdx.x;
        if (g * 4 < E) {
            int4 d = ((const int4*)dst)[g];
            int4 sv = ((const int4*)src)[g];
            int p;
            p = atomicAdd(&fill[d.x], 1); col[p] = sv.x;
            p = atomicAdd(&fill[d.y], 1); col[p] = sv.y;
            p = atomicAdd(&fill[d.z], 1); col[p] = sv.z;
            p = atomicAdd(&fill[d.w], 1); col[p] = sv.w;
        }
    } else {
        int gid = (bx / 3) * 2 + rem;          // 0..1023
        int n0 = (gid & 3) * 128;
        int m0 = (gid >> 2) * 128;
        gemm_body<true>(A, Bt, biasL, biasR, C, K, m0, n0, smem);
    }
}

// ---------------- standalone GEMM (layer 2, bf16 A) ----------------
__global__ __launch_bounds__(256) void k_gemm2(const bf16* __restrict__ A,
                                               const bf16* __restrict__ Bt,
                                               const float* __restrict__ biasL,
                                               const float* __restrict__ biasR,
                                               bf16* __restrict__ C, int K) {
    __shared__ bf16 smem[17408];
    int n0 = blockIdx.x * 128;
    int m0 = blockIdx.y * 128;
    gemm_body<false>(A, Bt, biasL, biasR, C, K, m0, n0, smem);
}

// ---------------- GATv2 aggregation: half-wave per edge, 8 ch/lane (R9 structure) ----------------
// One wave per dst node. Lanes 0-31 = item a, 32-63 = item b of each pair.
// Within a half: 8 lanes per head (hl>>3), 8 channels per lane ((hl&7)*8).
// Item 0 = self-loop, items 1..deg = CSR edges. Max-free softmax (logits bounded),
// leaky folded into att (0.6u + 0.4|u|). 32-bit element offsets (SGPR-base addressing).
__global__ __launch_bounds__(256) void k_agg(const bf16* __restrict__ xlr,
                                             const float* __restrict__ att,
                                             const int* __restrict__ row_ptr,
                                             const int* __restrict__ col,
                                             const float* __restrict__ bias,
                                             bf16* __restrict__ out, int do_gelu) {
    int wave = threadIdx.x >> 6, lane = threadIdx.x & 63;
    int i = blockIdx.x * 4 + wave;
    int hl = lane & 31;
    int half = lane >> 5;
    unsigned f = (hl >> 3) * 64 + (hl & 7) * 8;

    float att6[8], att4[8], xr_v[8];
    {
        floatx4 a0 = *(const floatx4*)(att + f);
        floatx4 a1 = *(const floatx4*)(att + f + 4);
        #pragma unroll
        for (int j = 0; j < 4; j++) {
            att6[j]     = 0.6f * a0[j]; att4[j]     = 0.4f * a0[j];
            att6[4 + j] = 0.6f * a1[j]; att4[4 + j] = 0.4f * a1[j];
        }
        bf16 t[8];
        *(short8*)t = *(const short8*)(xlr + ((unsigned)i * 512u + 256u + f));
        #pragma unroll
        for (int j = 0; j < 8; j++) xr_v[j] = b2f(t[j]);
    }

    int e0 = row_ptr[i], e1 = row_ptr[i + 1];
    int total = 1 + (e1 - e0);   // self + in-edges

    int src_c = i;
    if (half == 1 && total > 1) src_c = col[e0];
    bf16 g_cur[8];
    *(short8*)g_cur = *(const short8*)(xlr + ((unsigned)src_c * 512u + f));
    int t1 = 2 + half;
    int src_n = (t1 < total) ? col[e0 + t1 - 1] : i;

    float s = 0.f, acc[8] = {};

    for (int base = 0; base < total; base += 2) {
        bf16 g_nxt[8];
        *(short8*)g_nxt = *(const short8*)(xlr + ((unsigned)src_n * 512u + f));
        int t2 = base + 4 + half;
        int src_n2 = (t2 < total) ? col[e0 + t2 - 1] : i;
        bool valid = (base + half) < total;
        float xv[8], l = 0.f;
        #pragma unroll
        for (int j = 0; j < 8; j++) {
            xv[j] = b2f(g_cur[j]);
            float u = xv[j] + xr_v[j];
            l = fmaf(u, att6[j], fmaf(fabsf(u), att4[j], l));
        }
        l += __shfl_xor(l, 1, 8);
        l += __shfl_xor(l, 2, 8);
        l += __shfl_xor(l, 4, 8);
        float p = valid ? __expf(l) : 0.f;
        s += p;
        #pragma unroll
        for (int j = 0; j < 8; j++) acc[j] = fmaf(p, xv[j], acc[j]);
        #pragma unroll
        for (int j = 0; j < 8; j++) g_cur[j] = g_nxt[j];
        src_n = src_n2;
    }

    s += __shfl_xor(s, 32, 64);
    #pragma unroll
    for (int j = 0; j < 8; j++) acc[j] += __shfl_xor(acc[j], 32, 64);

    if (half == 0) {
        float inv = 1.0f / (s + 1e-16f);
        bf16 ov[8];
        #pragma unroll
        for (int j = 0; j < 8; j++) {
            float v = acc[j] * inv + bias[f + j];
            if (do_gelu) v = gelu_f(v);
            ov[j] = f2b(v);
        }
        *(short8*)(out + ((unsigned)i * 256u + f)) = *(const short8*)ov;
    }
}

// ---------------- shared head-layer body (block = one (graph, 64-col chunk)) ----------------
__device__ __forceinline__ void head_body(const bf16* __restrict__ inB,
                                          const float* __restrict__ inF,
                                          const float* __restrict__ W,
                                          const float* __restrict__ bias,
                                          float* __restrict__ out,
                                          int K, int N, long long row_stride, int act,
                                          int g, int chunk, float* zin, float* red) {
    int t = threadIdx.x;
    int nc = t & 63;
    int kq = t >> 6;
    int n = chunk * 64 + nc;
    for (int k = t; k < K; k += 256)
        zin[k] = inB ? b2f(inB[(size_t)g * row_stride + k])
                     : inF[(size_t)g * row_stride + k];
    __syncthreads();
    const int klen = K >> 2;
    const int kb = kq * klen;
    float acc = 0.f;
    #pragma unroll 8
    for (int k = 0; k < klen; k++)
        acc = fmaf(zin[kb + k], W[(size_t)(kb + k) * N + n], acc);
    red[t] = acc;
    __syncthreads();
    if (kq == 0) {
        float v = red[nc] + red[nc + 64] + red[nc + 128] + red[nc + 192] + bias[n];
        if (act) v = gelu_f(v);
        out[(size_t)g * N + n] = v;
    }
}

// ---------------- fused: pool stage 1 (blocks 0..511) + head lin1 (512..1535) ----------------
__global__ __launch_bounds__(256) void k_pe1(const bf16* __restrict__ hb,
                                             float* __restrict__ part,
                                             const float* __restrict__ lin1w,
                                             const float* __restrict__ lin1b,
                                             float* __restrict__ t1, int PG) {
    __shared__ float zin[256];
    __shared__ float red[256];
    int bx = blockIdx.x;
    if (bx < 512) {
        int g = bx >> 3, p = bx & 7, c = threadIdx.x;
        int rows_per = PG / 8;
        const bf16* base = hb + ((size_t)g * PG + (size_t)p * rows_per) * 256;
        float acc = 0.f;
        for (int r = 0; r < rows_per; r++) acc += b2f(base[(size_t)r * 256 + c]);
        part[((size_t)g * 8 + p) * 256 + c] = acc;
    } else {
        int b = bx - 512;
        head_body(hb, nullptr, lin1w, lin1b, t1, 256, 1024,
                  (long long)PG * 256, 1, b >> 4, b & 15, zin, red);
    }
}

// ---------------- fused: pool stage 2 (blocks 0..63) + head lin2 (64..319) ----------------
__global__ __launch_bounds__(256) void k_pe2(const float* __restrict__ part,
                                             float* __restrict__ outPool, int PG,
                                             const float* __restrict__ t1,
                                             const float* __restrict__ lin2w,
                                             const float* __restrict__ lin2b,
                                             float* __restrict__ t2) {
    __shared__ float zin[1024];
    __shared__ float red[256];
    int bx = blockIdx.x;
    if (bx < 64) {
        int g = bx, c = threadIdx.x;
        float acc = 0.f;
        for (int p = 0; p < 8; p++) acc += part[((size_t)g * 8 + p) * 256 + c];
        outPool[g * 256 + c] = acc / (float)PG;
    } else {
        int b = bx - 64;
        head_body(nullptr, t1, lin2w, lin2b, t2, 1024, 256,
                  1024, 0, b >> 2, b & 3, zin, red);
    }
}

// ---------------- final head layer ----------------
__global__ __launch_bounds__(256) void k_fin(const float* __restrict__ t2,
                                             const float* __restrict__ finw,
                                             const float* __restrict__ finb,
                                             float* __restrict__ out) {
    __shared__ float zin[256];
    __shared__ float red[256];
    head_body(nullptr, t2, finw, finb, out, 256, 512,
              256, 0, blockIdx.x, blockIdx.y, zin, red);
}

extern "C" void kernel_launch(void* const* d_in, const int* in_sizes, int n_in,
                              void* d_out, int out_size, void* d_ws, size_t ws_size,
                              hipStream_t stream) {
    const float* x     = (const float*)d_in[0];
    const int*   ei    = (const int*)d_in[1];
    const float* w1_l  = (const float*)d_in[4];
    const float* b1_l  = (const float*)d_in[5];
    const float* w1_r  = (const float*)d_in[6];
    const float* b1_r  = (const float*)d_in[7];
    const float* att1  = (const float*)d_in[8];
    const float* bias1 = (const float*)d_in[9];
    const float* w2_l  = (const float*)d_in[10];
    const float* b2_l  = (const float*)d_in[11];
    const float* w2_r  = (const float*)d_in[12];
    const float* b2_r  = (const float*)d_in[13];
    const float* att2  = (const float*)d_in[14];
    const float* bias2 = (const float*)d_in[15];
    const float* lin1w = (const float*)d_in[16];
    const float* lin1b = (const float*)d_in[17];
    const float* lin2w = (const float*)d_in[18];
    const float* lin2b = (const float*)d_in[19];
    const float* finw  = (const float*)d_in[20];
    const float* finb  = (const float*)d_in[21];

    const int N  = in_sizes[0] / 256;   // 32768
    const int E  = in_sizes[1] / 2;     // 524288
    const int NG = 64;
    const int PG = N / NG;              // 512

    // workspace layout (~52.5 MiB)
    char* ws = (char*)d_ws;
    size_t off = 0;
    bf16* xlr = (bf16*)(ws + off); off += (size_t)N * 512 * 2;    // 32 MiB [xl|xr]
    bf16* hb  = (bf16*)(ws + off); off += (size_t)N * 256 * 2;    // 16 MiB (h1 then h2)
    bf16* wt  = (bf16*)(ws + off); off += 2 * 512 * 256 * 2;      // 512 KiB both layers' Wt
    int* row_ptr = (int*)(ws + off); off += (size_t)(N + 4) * 4;
    int* cnt     = (int*)(ws + off); off += (size_t)N * 4;
    int* fill    = (int*)(ws + off); off += (size_t)N * 4;
    int* col     = (int*)(ws + off); off += (size_t)E * 4;
    float* pws   = (float*)(ws + off); off += (size_t)NG * 8 * 256 * 4;  // pool partials
    float* t1    = (float*)(ws + off); off += (size_t)NG * 1024 * 4;
    float* t2    = (float*)(ws + off); off += (size_t)NG * 256 * 4;

    const int* srcv = ei;
    const int* dstv = ei + E;

    // --- CSR count + weight transposes (one launch) ---
    hipMemsetAsync(cnt, 0, (size_t)N * 4, stream);
    k_count_tr<<<512 + 1024, 256, 0, stream>>>(dstv, cnt, E,
                                               w1_l, w1_r, w2_l, w2_r, wt);
    k_scan<<<1, 1024, 0, stream>>>(cnt, row_ptr, fill, N);

    // --- scatter + layer-1 GEMM (one union launch, roles interleaved) ---
    k_scatter_gemm<<<512 + 1024, 256, 0, stream>>>(srcv, dstv, fill, col, E,
                                                   x, wt, b1_l, b1_r, xlr, 256);
    k_agg<<<N / 4, 256, 0, stream>>>(xlr, att1, row_ptr, col, bias1, hb, 1);  // + GELU

    // --- layer 2 (A = h1 bf16) ---
    dim3 gg(4, N / 128);
    k_gemm2<<<gg, 256, 0, stream>>>(hb, wt + 512 * 256, b2_l, b2_r, xlr, 256);
    k_agg<<<N / 4, 256, 0, stream>>>(xlr, att2, row_ptr, col, bias2, hb, 0);  // h2

    float* outp = (float*)d_out;
    // --- pool1 + head lin1 (one launch) ---
    k_pe1<<<512 + 1024, 256, 0, stream>>>(hb, pws, lin1w, lin1b, t1, PG);
    // --- pool2 (-> d_out[64*512..]) + head lin2 (one launch) ---
    k_pe2<<<64 + 256, 256, 0, stream>>>(pws, outp + 64 * 512, PG, t1, lin2w, lin2b, t2);
    // --- final head layer -> d_out[0..64*512) ---
    dim3 gf(NG, 512 / 64);
    k_fin<<<gf, 256, 0, stream>>>(t2, finw, finb, outp);
}

// Round 15
// 338.044 us; speedup vs baseline: 2.4533x; 1.0360x over previous
//
#include <hip/hip_runtime.h>
#include <hip/hip_bf16.h>
#include <stdint.h>

typedef __attribute__((ext_vector_type(8))) short short8;
typedef __attribute__((ext_vector_type(4))) short short4v;
typedef __attribute__((ext_vector_type(4))) float floatx4;
typedef __attribute__((ext_vector_type(2))) float floatx2;
typedef __hip_bfloat16 bf16;

__device__ __forceinline__ float b2f(bf16 v) { return __bfloat162float(v); }
__device__ __forceinline__ bf16 f2b(float v) { return __float2bfloat16(v); }
__device__ __forceinline__ float gelu_f(float v) {
    return 0.5f * v * (1.0f + erff(v * 0.70710678118654752f));
}
// two packed bf16 (one dword) -> two fp32, exact (<<16)
__device__ __forceinline__ floatx2 cvt2(unsigned v) {
    floatx2 r;
    r.x = __uint_as_float(v << 16);
    r.y = __uint_as_float(v & 0xffff0000u);
    return r;
}

#define GLD_LDS16(gptr, lptr) \
  __builtin_amdgcn_global_load_lds((const __attribute__((address_space(1))) void*)(gptr), \
                                   (__attribute__((address_space(3))) void*)(lptr), 16, 0, 0)

// NOTE (R12 lesson): hipLaunchCooperativeKernel grid.sync() costs ~60us each on this
// stack under graph capture -- ~10x a dispatch gap. Never fuse via grid.sync here.
// NOTE (R13 lesson): epilogue LDS tile stride must be 16B-aligned (132 elems = 264B
// broke ds_read_b128 alignment -> 3.1M conflict cycles). Use 136 elems = 272B.

// ---------------- fused: CSR count (blocks 0..511) + weight transposes (512..1535) ----------------
__global__ void k_count_tr(const int* __restrict__ dst, int* __restrict__ cnt, int E,
                           const float* __restrict__ Wl1, const float* __restrict__ Wr1,
                           const float* __restrict__ Wl2, const float* __restrict__ Wr2,
                           bf16* __restrict__ Wt) {
    int bx = blockIdx.x;
    if (bx < 512) {
        int g = bx * 256 + threadIdx.x;
        if (g * 4 < E) {
            int4 d = ((const int4*)dst)[g];
            atomicAdd(&cnt[d.x], 1);
            atomicAdd(&cnt[d.y], 1);
            atomicAdd(&cnt[d.z], 1);
            atomicAdd(&cnt[d.w], 1);
        }
    } else {
        int b = bx - 512;
        int r = b & 255, half = (b >> 8) & 1, layer = b >> 9;
        int c = threadIdx.x;
        const float* W = layer ? (half ? Wr2 : Wl2) : (half ? Wr1 : Wl1);
        Wt[(size_t)(layer * 512 + half * 256 + c) * 256 + r] = f2b(W[r * 256 + c]);
    }
}

// n must be 32768: 1024 threads x 32 elements each (int4 loads)
__global__ __launch_bounds__(1024) void k_scan(const int* __restrict__ cnt,
                                               int* __restrict__ row_ptr,
                                               int* __restrict__ fill, int n) {
    __shared__ int sdata[1024];
    int t = threadIdx.x;
    int base = t * 32;
    int local[32];
    const int4* c4 = (const int4*)(cnt + base);
    int vals[32];
    #pragma unroll
    for (int q = 0; q < 8; q++) {
        int4 v = c4[q];
        vals[q * 4 + 0] = v.x; vals[q * 4 + 1] = v.y;
        vals[q * 4 + 2] = v.z; vals[q * 4 + 3] = v.w;
    }
    int sum = 0;
    #pragma unroll
    for (int k = 0; k < 32; k++) { local[k] = sum; sum += vals[k]; }
    sdata[t] = sum;
    __syncthreads();
    for (int off = 1; off < 1024; off <<= 1) {
        int v = (t >= off) ? sdata[t - off] : 0;
        __syncthreads();
        sdata[t] += v;
        __syncthreads();
    }
    int excl = sdata[t] - sum;
    #pragma unroll
    for (int k = 0; k < 32; k++) {
        int v = excl + local[k];
        row_ptr[base + k] = v;
        fill[base + k] = v;
    }
    if (t == 1023) row_ptr[n] = excl + sum;
}

// ---------------- GEMM tile body: C[M,512] = A[M,K] @ Bt[512,K]^T + bias ----------------
template <bool AF32>
__device__ __forceinline__ void gemm_body(const void* __restrict__ Av,
                                          const bf16* __restrict__ Bt,
                                          const float* __restrict__ biasL,
                                          const float* __restrict__ biasR,
                                          bf16* __restrict__ C,
                                          int K, int m0, int n0,
                                          bf16* __restrict__ smem) {
    bf16* As = smem;
    bf16* Bs = smem + 8192;
    const int tid  = threadIdx.x;
    const int wave = tid >> 6;
    const int lane = tid & 63;
    const int quad = lane >> 4;
    const int l16  = lane & 15;
    const int wm = (wave & 1) * 64;
    const int wn = (wave >> 1) * 64;

    floatx4 acc[4][4] = {};

    for (int k0 = 0; k0 < K; k0 += 64) {
        #pragma unroll
        for (int i = 0; i < 4; i++) {
            if (AF32) {
                const float* A = (const float*)Av;
                int flat = (i * 256 + tid) * 8;
                int row  = flat >> 6;
                int colk = flat & 63;
                const float* ap = A + (size_t)(m0 + row) * K + k0 + colk;
                bf16 tmp[8];
                #pragma unroll
                for (int q = 0; q < 8; q++) tmp[q] = f2b(ap[q]);
                *(short8*)&As[row * 64 + colk] = *(const short8*)tmp;
            } else {
                const bf16* A = (const bf16*)Av;
                int chunk = i * 4 + wave;
                int foff  = (chunk * 64 + lane) * 16;
                int row   = foff >> 7;
                int cole  = (foff & 127) >> 1;
                GLD_LDS16(A + (size_t)(m0 + row) * K + k0 + cole,
                          (char*)As + chunk * 1024 + lane * 16);
            }
            {
                int chunk = i * 4 + wave;
                int foff  = (chunk * 64 + lane) * 16;
                int row   = foff >> 7;
                int cole  = (foff & 127) >> 1;
                GLD_LDS16(Bt + (size_t)(n0 + row) * K + k0 + cole,
                          (char*)Bs + chunk * 1024 + lane * 16);
            }
        }
        __syncthreads();
        #pragma unroll
        for (int ks = 0; ks < 2; ks++) {
            short8 af[4], bfr[4];
            #pragma unroll
            for (int i = 0; i < 4; i++) {
                af[i]  = *(const short8*)&As[(wm + i * 16 + l16) * 64 + ks * 32 + quad * 8];
                bfr[i] = *(const short8*)&Bs[(wn + i * 16 + l16) * 64 + ks * 32 + quad * 8];
            }
            #pragma unroll
            for (int i = 0; i < 4; i++)
                #pragma unroll
                for (int j = 0; j < 4; j++)
                    acc[i][j] = __builtin_amdgcn_mfma_f32_16x16x32_bf16(af[i], bfr[j], acc[i][j], 0, 0, 0);
        }
        __syncthreads();
    }

    // C/D layout: col = lane&15, row = quad*4 + reg  [verified m89/m91]
    #pragma unroll
    for (int j = 0; j < 4; j++) {
        int lcol = wn + j * 16 + l16;
        int gcol = n0 + lcol;
        float bv = (gcol < 256) ? biasL[gcol] : biasR[gcol - 256];
        #pragma unroll
        for (int i = 0; i < 4; i++) {
            #pragma unroll
            for (int r = 0; r < 4; r++) {
                int lrow = wm + i * 16 + quad * 4 + r;
                smem[lrow * 136 + lcol] = f2b(acc[i][j][r] + bv);
            }
        }
    }
    __syncthreads();
    {
        int rl = tid >> 4;
        int cs = (tid & 15) * 8;
        #pragma unroll
        for (int p = 0; p < 8; p++) {
            int row = p * 16 + rl;
            short8 v = *(const short8*)&smem[row * 136 + cs];
            *(short8*)(C + (size_t)(m0 + row) * 512 + n0 + cs) = v;
        }
    }
}

// ---------------- union dispatch: scatter + layer-1 GEMM, roles interleaved ----------------
__global__ __launch_bounds__(256) void k_scatter_gemm(const int* __restrict__ src,
                                                      const int* __restrict__ dst,
                                                      int* __restrict__ fill,
                                                      int* __restrict__ col, int E,
                                                      const float* __restrict__ A,
                                                      const bf16* __restrict__ Bt,
                                                      const float* __restrict__ biasL,
                                                      const float* __restrict__ biasR,
                                                      bf16* __restrict__ C, int K) {
    __shared__ bf16 smem[17408];
    int bx = blockIdx.x;
    int rem = bx % 3;
    if (rem == 2) {
        int g = (bx / 3) * 256 + threadIdx.x;
        if (g * 4 < E) {
            int4 d = ((const int4*)dst)[g];
            int4 sv = ((const int4*)src)[g];
            int p;
            p = atomicAdd(&fill[d.x], 1); col[p] = sv.x;
            p = atomicAdd(&fill[d.y], 1); col[p] = sv.y;
            p = atomicAdd(&fill[d.z], 1); col[p] = sv.z;
            p = atomicAdd(&fill[d.w], 1); col[p] = sv.w;
        }
    } else {
        int gid = (bx / 3) * 2 + rem;
        int n0 = (gid & 3) * 128;
        int m0 = (gid >> 2) * 128;
        gemm_body<true>(A, Bt, biasL, biasR, C, K, m0, n0, smem);
    }
}

// ---------------- standalone GEMM (layer 2, bf16 A) ----------------
__global__ __launch_bounds__(256) void k_gemm2(const bf16* __restrict__ A,
                                               const bf16* __restrict__ Bt,
                                               const float* __restrict__ biasL,
                                               const float* __restrict__ biasR,
                                               bf16* __restrict__ C, int K) {
    __shared__ bf16 smem[17408];
    int n0 = blockIdx.x * 128;
    int m0 = blockIdx.y * 128;
    gemm_body<false>(A, Bt, biasL, biasR, C, K, m0, n0, smem);
}

// ---------------- GATv2 aggregation: half-wave per edge, 8 ch/lane, PACKED fp32 math ----------
// One wave per dst node. Lanes 0-31 = item a, 32-63 = item b of each pair.
// Within a half: 8 lanes per head (hl>>3), 8 channels per lane ((hl&7)*8) = 4 float2 pairs.
// Channel math on ext_vector(2) floats -> v_pk_{add,fma,max}_f32 (2 ch/inst).
// Item 0 = self-loop. Max-free softmax (logits bounded), leaky = 0.6u + 0.4|u| folded into att.
__global__ __launch_bounds__(256) void k_agg(const bf16* __restrict__ xlr,
                                             const float* __restrict__ att,
                                             const int* __restrict__ row_ptr,
                                             const int* __restrict__ col,
                                             const float* __restrict__ bias,
                                             bf16* __restrict__ out, int do_gelu) {
    int wave = threadIdx.x >> 6, lane = threadIdx.x & 63;
    int i = blockIdx.x * 4 + wave;
    int hl = lane & 31;
    int half = lane >> 5;
    unsigned f = (hl >> 3) * 64 + (hl & 7) * 8;

    floatx2 att6v[4], att4v[4], xrv[4];
    {
        floatx4 a0 = *(const floatx4*)(att + f);
        floatx4 a1 = *(const floatx4*)(att + f + 4);
        att6v[0] = (floatx2){0.6f * a0[0], 0.6f * a0[1]};
        att6v[1] = (floatx2){0.6f * a0[2], 0.6f * a0[3]};
        att6v[2] = (floatx2){0.6f * a1[0], 0.6f * a1[1]};
        att6v[3] = (floatx2){0.6f * a1[2], 0.6f * a1[3]};
        att4v[0] = (floatx2){0.4f * a0[0], 0.4f * a0[1]};
        att4v[1] = (floatx2){0.4f * a0[2], 0.4f * a0[3]};
        att4v[2] = (floatx2){0.4f * a1[0], 0.4f * a1[1]};
        att4v[3] = (floatx2){0.4f * a1[2], 0.4f * a1[3]};
        unsigned raw[4];
        *(uint4*)raw = *(const uint4*)(xlr + ((unsigned)i * 512u + 256u + f));
        #pragma unroll
        for (int k = 0; k < 4; k++) xrv[k] = cvt2(raw[k]);
    }

    int e0 = row_ptr[i], e1 = row_ptr[i + 1];
    int total = 1 + (e1 - e0);   // self + in-edges

    int src_c = i;
    if (half == 1 && total > 1) src_c = col[e0];
    unsigned g_cur[4];
    *(uint4*)g_cur = *(const uint4*)(xlr + ((unsigned)src_c * 512u + f));
    int t1 = 2 + half;
    int src_n = (t1 < total) ? col[e0 + t1 - 1] : i;

    float s = 0.f;
    floatx2 acc2[4] = {};

    for (int base = 0; base < total; base += 2) {
        unsigned g_nxt[4];
        *(uint4*)g_nxt = *(const uint4*)(xlr + ((unsigned)src_n * 512u + f));
        int t2 = base + 4 + half;
        int src_n2 = (t2 < total) ? col[e0 + t2 - 1] : i;
        bool valid = (base + half) < total;
        floatx2 xv[4], l2 = {0.f, 0.f};
        #pragma unroll
        for (int k = 0; k < 4; k++) {
            xv[k] = cvt2(g_cur[k]);
            floatx2 u = xv[k] + xrv[k];           // v_pk_add_f32
            floatx2 au = __builtin_elementwise_abs(u);
            l2 += u * att6v[k];                   // v_pk_fma_f32
            l2 += au * att4v[k];                  // v_pk_fma_f32
        }
        float l = l2.x + l2.y;
        l += __shfl_xor(l, 1, 8);
        l += __shfl_xor(l, 2, 8);
        l += __shfl_xor(l, 4, 8);
        float p = valid ? __expf(l) : 0.f;
        s += p;
        floatx2 p2 = {p, p};
        #pragma unroll
        for (int k = 0; k < 4; k++) acc2[k] += p2 * xv[k];   // v_pk_fma_f32
        #pragma unroll
        for (int k = 0; k < 4; k++) g_cur[k] = g_nxt[k];
        src_n = src_n2;
    }

    // combine the two halves
    s += __shfl_xor(s, 32, 64);
    #pragma unroll
    for (int k = 0; k < 4; k++) {
        acc2[k].x += __shfl_xor(acc2[k].x, 32, 64);
        acc2[k].y += __shfl_xor(acc2[k].y, 32, 64);
    }

    if (half == 0) {
        float inv = 1.0f / (s + 1e-16f);
        bf16 ov[8];
        #pragma unroll
        for (int k = 0; k < 4; k++) {
            float v0 = acc2[k].x * inv + bias[f + 2 * k];
            float v1 = acc2[k].y * inv + bias[f + 2 * k + 1];
            if (do_gelu) { v0 = gelu_f(v0); v1 = gelu_f(v1); }
            ov[2 * k]     = f2b(v0);
            ov[2 * k + 1] = f2b(v1);
        }
        *(short8*)(out + ((unsigned)i * 256u + f)) = *(const short8*)ov;
    }
}

// ---------------- shared head-layer body (block = one (graph, 64-col chunk)) ----------------
__device__ __forceinline__ void head_body(const bf16* __restrict__ inB,
                                          const float* __restrict__ inF,
                                          const float* __restrict__ W,
                                          const float* __restrict__ bias,
                                          float* __restrict__ out,
                                          int K, int N, long long row_stride, int act,
                                          int g, int chunk, float* zin, float* red) {
    int t = threadIdx.x;
    int nc = t & 63;
    int kq = t >> 6;
    int n = chunk * 64 + nc;
    for (int k = t; k < K; k += 256)
        zin[k] = inB ? b2f(inB[(size_t)g * row_stride + k])
                     : inF[(size_t)g * row_stride + k];
    __syncthreads();
    const int klen = K >> 2;
    const int kb = kq * klen;
    float acc = 0.f;
    #pragma unroll 8
    for (int k = 0; k < klen; k++)
        acc = fmaf(zin[kb + k], W[(size_t)(kb + k) * N + n], acc);
    red[t] = acc;
    __syncthreads();
    if (kq == 0) {
        float v = red[nc] + red[nc + 64] + red[nc + 128] + red[nc + 192] + bias[n];
        if (act) v = gelu_f(v);
        out[(size_t)g * N + n] = v;
    }
}

// ---------------- fused: pool stage 1 (blocks 0..511) + head lin1 (512..1535) ----------------
__global__ __launch_bounds__(256) void k_pe1(const bf16* __restrict__ hb,
                                             float* __restrict__ part,
                                             const float* __restrict__ lin1w,
                                             const float* __restrict__ lin1b,
                                             float* __restrict__ t1, int PG) {
    __shared__ float zin[256];
    __shared__ float red[256];
    int bx = blockIdx.x;
    if (bx < 512) {
        int g = bx >> 3, p = bx & 7, c = threadIdx.x;
        int rows_per = PG / 8;
        const bf16* base = hb + ((size_t)g * PG + (size_t)p * rows_per) * 256;
        float acc = 0.f;
        for (int r = 0; r < rows_per; r++) acc += b2f(base[(size_t)r * 256 + c]);
        part[((size_t)g * 8 + p) * 256 + c] = acc;
    } else {
        int b = bx - 512;
        head_body(hb, nullptr, lin1w, lin1b, t1, 256, 1024,
                  (long long)PG * 256, 1, b >> 4, b & 15, zin, red);
    }
}

// ---------------- fused: pool stage 2 (blocks 0..63) + head lin2 (64..319) ----------------
__global__ __launch_bounds__(256) void k_pe2(const float* __restrict__ part,
                                             float* __restrict__ outPool, int PG,
                                             const float* __restrict__ t1,
                                             const float* __restrict__ lin2w,
                                             const float* __restrict__ lin2b,
                                             float* __restrict__ t2) {
    __shared__ float zin[1024];
    __shared__ float red[256];
    int bx = blockIdx.x;
    if (bx < 64) {
        int g = bx, c = threadIdx.x;
        float acc = 0.f;
        for (int p = 0; p < 8; p++) acc += part[((size_t)g * 8 + p) * 256 + c];
        outPool[g * 256 + c] = acc / (float)PG;
    } else {
        int b = bx - 64;
        head_body(nullptr, t1, lin2w, lin2b, t2, 1024, 256,
                  1024, 0, b >> 2, b & 3, zin, red);
    }
}

// ---------------- final head layer ----------------
__global__ __launch_bounds__(256) void k_fin(const float* __restrict__ t2,
                                             const float* __restrict__ finw,
                                             const float* __restrict__ finb,
                                             float* __restrict__ out) {
    __shared__ float zin[256];
    __shared__ float red[256];
    head_body(nullptr, t2, finw, finb, out, 256, 512,
              256, 0, blockIdx.x, blockIdx.y, zin, red);
}

extern "C" void kernel_launch(void* const* d_in, const int* in_sizes, int n_in,
                              void* d_out, int out_size, void* d_ws, size_t ws_size,
                              hipStream_t stream) {
    const float* x     = (const float*)d_in[0];
    const int*   ei    = (const int*)d_in[1];
    const float* w1_l  = (const float*)d_in[4];
    const float* b1_l  = (const float*)d_in[5];
    const float* w1_r  = (const float*)d_in[6];
    const float* b1_r  = (const float*)d_in[7];
    const float* att1  = (const float*)d_in[8];
    const float* bias1 = (const float*)d_in[9];
    const float* w2_l  = (const float*)d_in[10];
    const float* b2_l  = (const float*)d_in[11];
    const float* w2_r  = (const float*)d_in[12];
    const float* b2_r  = (const float*)d_in[13];
    const float* att2  = (const float*)d_in[14];
    const float* bias2 = (const float*)d_in[15];
    const float* lin1w = (const float*)d_in[16];
    const float* lin1b = (const float*)d_in[17];
    const float* lin2w = (const float*)d_in[18];
    const float* lin2b = (const float*)d_in[19];
    const float* finw  = (const float*)d_in[20];
    const float* finb  = (const float*)d_in[21];

    const int N  = in_sizes[0] / 256;   // 32768
    const int E  = in_sizes[1] / 2;     // 524288
    const int NG = 64;
    const int PG = N / NG;              // 512

    // workspace layout (~52.5 MiB)
    char* ws = (char*)d_ws;
    size_t off = 0;
    bf16* xlr = (bf16*)(ws + off); off += (size_t)N * 512 * 2;    // 32 MiB [xl|xr]
    bf16* hb  = (bf16*)(ws + off); off += (size_t)N * 256 * 2;    // 16 MiB (h1 then h2)
    bf16* wt  = (bf16*)(ws + off); off += 2 * 512 * 256 * 2;      // 512 KiB both layers' Wt
    int* row_ptr = (int*)(ws + off); off += (size_t)(N + 4) * 4;
    int* cnt     = (int*)(ws + off); off += (size_t)N * 4;
    int* fill    = (int*)(ws + off); off += (size_t)N * 4;
    int* col     = (int*)(ws + off); off += (size_t)E * 4;
    float* pws   = (float*)(ws + off); off += (size_t)NG * 8 * 256 * 4;  // pool partials
    float* t1    = (float*)(ws + off); off += (size_t)NG * 1024 * 4;
    float* t2    = (float*)(ws + off); off += (size_t)NG * 256 * 4;

    const int* srcv = ei;
    const int* dstv = ei + E;

    // --- CSR count + weight transposes (one launch) ---
    hipMemsetAsync(cnt, 0, (size_t)N * 4, stream);
    k_count_tr<<<512 + 1024, 256, 0, stream>>>(dstv, cnt, E,
                                               w1_l, w1_r, w2_l, w2_r, wt);
    k_scan<<<1, 1024, 0, stream>>>(cnt, row_ptr, fill, N);

    // --- scatter + layer-1 GEMM (one union launch, roles interleaved) ---
    k_scatter_gemm<<<512 + 1024, 256, 0, stream>>>(srcv, dstv, fill, col, E,
                                                   x, wt, b1_l, b1_r, xlr, 256);
    k_agg<<<N / 4, 256, 0, stream>>>(xlr, att1, row_ptr, col, bias1, hb, 1);  // + GELU

    // --- layer 2 (A = h1 bf16) ---
    dim3 gg(4, N / 128);
    k_gemm2<<<gg, 256, 0, stream>>>(hb, wt + 512 * 256, b2_l, b2_r, xlr, 256);
    k_agg<<<N / 4, 256, 0, stream>>>(xlr, att2, row_ptr, col, bias2, hb, 0);  // h2

    float* outp = (float*)d_out;
    // --- pool1 + head lin1 (one launch) ---
    k_pe1<<<512 + 1024, 256, 0, stream>>>(hb, pws, lin1w, lin1b, t1, PG);
    // --- pool2 (-> d_out[64*512..]) + head lin2 (one launch) ---
    k_pe2<<<64 + 256, 256, 0, stream>>>(pws, outp + 64 * 512, PG, t1, lin2w, lin2b, t2);
    // --- final head layer -> d_out[0..64*512) ---
    dim3 gf(NG, 512 / 64);
    k_fin<<<gf, 256, 0, stream>>>(t2, finw, finb, outp);
}

// Round 16
// 332.181 us; speedup vs baseline: 2.4966x; 1.0177x over previous
//
#include <hip/hip_runtime.h>
#include <hip/hip_bf16.h>
#include <stdint.h>

typedef __attribute__((ext_vector_type(8))) short short8;
typedef __attribute__((ext_vector_type(4))) short short4v;
typedef __attribute__((ext_vector_type(4))) float floatx4;
typedef __attribute__((ext_vector_type(2))) float floatx2;
typedef __hip_bfloat16 bf16;

__device__ __forceinline__ float b2f(bf16 v) { return __bfloat162float(v); }
__device__ __forceinline__ bf16 f2b(float v) { return __float2bfloat16(v); }
__device__ __forceinline__ float gelu_f(float v) {
    return 0.5f * v * (1.0f + erff(v * 0.70710678118654752f));
}
// two packed bf16 (one dword) -> two fp32, exact (<<16)
__device__ __forceinline__ floatx2 cvt2(unsigned v) {
    floatx2 r;
    r.x = __uint_as_float(v << 16);
    r.y = __uint_as_float(v & 0xffff0000u);
    return r;
}

#define GLD_LDS16(gptr, lptr) \
  __builtin_amdgcn_global_load_lds((const __attribute__((address_space(1))) void*)(gptr), \
                                   (__attribute__((address_space(3))) void*)(lptr), 16, 0, 0)

// NOTE (R12): cooperative grid.sync() costs ~60us each here -- never fuse via grid.sync.
// NOTE (R15): GEMM LDS conflicts came from fragment reads (row pitch 128B = 32 banks ->
// 16-way quad conflicts), NOT the epilogue stride. Fix = XOR-swizzle 16B chunks:
// physical slot = logical_chunk ^ (row&7). global_load_lds forces dest=base+lane*16,
// so the swizzle is applied to the SOURCE k-offset instead.

// ---------------- fused: CSR count (blocks 0..511) + weight transposes (512..1535) ----------------
__global__ void k_count_tr(const int* __restrict__ dst, int* __restrict__ cnt, int E,
                           const float* __restrict__ Wl1, const float* __restrict__ Wr1,
                           const float* __restrict__ Wl2, const float* __restrict__ Wr2,
                           bf16* __restrict__ Wt) {
    int bx = blockIdx.x;
    if (bx < 512) {
        int g = bx * 256 + threadIdx.x;
        if (g * 4 < E) {
            int4 d = ((const int4*)dst)[g];
            atomicAdd(&cnt[d.x], 1);
            atomicAdd(&cnt[d.y], 1);
            atomicAdd(&cnt[d.z], 1);
            atomicAdd(&cnt[d.w], 1);
        }
    } else {
        int b = bx - 512;
        int r = b & 255, half = (b >> 8) & 1, layer = b >> 9;
        int c = threadIdx.x;
        const float* W = layer ? (half ? Wr2 : Wl2) : (half ? Wr1 : Wl1);
        Wt[(size_t)(layer * 512 + half * 256 + c) * 256 + r] = f2b(W[r * 256 + c]);
    }
}

// n must be 32768: 1024 threads x 32 elements each (int4 loads)
__global__ __launch_bounds__(1024) void k_scan(const int* __restrict__ cnt,
                                               int* __restrict__ row_ptr,
                                               int* __restrict__ fill, int n) {
    __shared__ int sdata[1024];
    int t = threadIdx.x;
    int base = t * 32;
    int local[32];
    const int4* c4 = (const int4*)(cnt + base);
    int vals[32];
    #pragma unroll
    for (int q = 0; q < 8; q++) {
        int4 v = c4[q];
        vals[q * 4 + 0] = v.x; vals[q * 4 + 1] = v.y;
        vals[q * 4 + 2] = v.z; vals[q * 4 + 3] = v.w;
    }
    int sum = 0;
    #pragma unroll
    for (int k = 0; k < 32; k++) { local[k] = sum; sum += vals[k]; }
    sdata[t] = sum;
    __syncthreads();
    for (int off = 1; off < 1024; off <<= 1) {
        int v = (t >= off) ? sdata[t - off] : 0;
        __syncthreads();
        sdata[t] += v;
        __syncthreads();
    }
    int excl = sdata[t] - sum;
    #pragma unroll
    for (int k = 0; k < 32; k++) {
        int v = excl + local[k];
        row_ptr[base + k] = v;
        fill[base + k] = v;
    }
    if (t == 1023) row_ptr[n] = excl + sum;
}

// ---------------- GEMM tile body: C[M,512] = A[M,K] @ Bt[512,K]^T + bias ----------------
// 128x128 tile, BK=64, XOR-swizzled LDS (physical 16B chunk = logical ^ (row&7)).
template <bool AF32>
__device__ __forceinline__ void gemm_body(const void* __restrict__ Av,
                                          const bf16* __restrict__ Bt,
                                          const float* __restrict__ biasL,
                                          const float* __restrict__ biasR,
                                          bf16* __restrict__ C,
                                          int K, int m0, int n0,
                                          bf16* __restrict__ smem) {
    bf16* As = smem;
    bf16* Bs = smem + 8192;
    const int tid  = threadIdx.x;
    const int wave = tid >> 6;
    const int lane = tid & 63;
    const int quad = lane >> 4;
    const int l16  = lane & 15;
    const int wm = (wave & 1) * 64;
    const int wn = (wave >> 1) * 64;
    // source k-offset for swizzled global_load_lds staging (dest slot lane&7, row lane>>3)
    const int scole = ((lane & 7) ^ (lane >> 3)) * 8;
    const int srow  = lane >> 3;

    floatx4 acc[4][4] = {};

    for (int k0 = 0; k0 < K; k0 += 64) {
        #pragma unroll
        for (int i = 0; i < 4; i++) {
            int chunk = i * 4 + wave;                 // 16 chunks of 1 KB (8 rows) each
            if (AF32) {
                const float* A = (const float*)Av;
                int flat = (i * 256 + tid) * 8;
                int row  = flat >> 6;
                int colk = (tid & 7) * 8;             // logical chunk (tid&7)
                const float* ap = A + (size_t)(m0 + row) * K + k0 + colk;
                bf16 tmp[8];
                #pragma unroll
                for (int q = 0; q < 8; q++) tmp[q] = f2b(ap[q]);
                int pcol = (((tid & 7) ^ (row & 7)) * 8);   // swizzled physical slot
                *(short8*)&As[row * 64 + pcol] = *(const short8*)tmp;
            } else {
                const bf16* A = (const bf16*)Av;
                int row = chunk * 8 + srow;
                GLD_LDS16(A + (size_t)(m0 + row) * K + k0 + scole,
                          (char*)As + chunk * 1024 + lane * 16);
            }
            {
                int row = chunk * 8 + srow;
                GLD_LDS16(Bt + (size_t)(n0 + row) * K + k0 + scole,
                          (char*)Bs + chunk * 1024 + lane * 16);
            }
        }
        __syncthreads();
        #pragma unroll
        for (int ks = 0; ks < 2; ks++) {
            short8 af[4], bfr[4];
            int pk = ((ks * 4 + quad) ^ (l16 & 7)) * 8;   // swizzled fragment k-offset
            #pragma unroll
            for (int i = 0; i < 4; i++) {
                af[i]  = *(const short8*)&As[(wm + i * 16 + l16) * 64 + pk];
                bfr[i] = *(const short8*)&Bs[(wn + i * 16 + l16) * 64 + pk];
            }
            #pragma unroll
            for (int i = 0; i < 4; i++)
                #pragma unroll
                for (int j = 0; j < 4; j++)
                    acc[i][j] = __builtin_amdgcn_mfma_f32_16x16x32_bf16(af[i], bfr[j], acc[i][j], 0, 0, 0);
        }
        __syncthreads();
    }

    // C/D layout: col = lane&15, row = quad*4 + reg  [verified m89/m91]
    #pragma unroll
    for (int j = 0; j < 4; j++) {
        int lcol = wn + j * 16 + l16;
        int gcol = n0 + lcol;
        float bv = (gcol < 256) ? biasL[gcol] : biasR[gcol - 256];
        #pragma unroll
        for (int i = 0; i < 4; i++) {
            #pragma unroll
            for (int r = 0; r < 4; r++) {
                int lrow = wm + i * 16 + quad * 4 + r;
                smem[lrow * 136 + lcol] = f2b(acc[i][j][r] + bv);
            }
        }
    }
    __syncthreads();
    {
        int rl = tid >> 4;
        int cs = (tid & 15) * 8;
        #pragma unroll
        for (int p = 0; p < 8; p++) {
            int row = p * 16 + rl;
            short8 v = *(const short8*)&smem[row * 136 + cs];
            *(short8*)(C + (size_t)(m0 + row) * 512 + n0 + cs) = v;
        }
    }
}

// ---------------- union dispatch: scatter + layer-1 GEMM, roles interleaved ----------------
__global__ __launch_bounds__(256) void k_scatter_gemm(const int* __restrict__ src,
                                                      const int* __restrict__ dst,
                                                      int* __restrict__ fill,
                                                      int* __restrict__ col, int E,
                                                      const float* __restrict__ A,
                                                      const bf16* __restrict__ Bt,
                                                      const float* __restrict__ biasL,
                                                      const float* __restrict__ biasR,
                                                      bf16* __restrict__ C, int K) {
    __shared__ bf16 smem[17408];
    int bx = blockIdx.x;
    int rem = bx % 3;
    if (rem == 2) {
        int g = (bx / 3) * 256 + threadIdx.x;
        if (g * 4 < E) {
            int4 d = ((const int4*)dst)[g];
            int4 sv = ((const int4*)src)[g];
            int p;
            p = atomicAdd(&fill[d.x], 1); col[p] = sv.x;
            p = atomicAdd(&fill[d.y], 1); col[p] = sv.y;
            p = atomicAdd(&fill[d.z], 1); col[p] = sv.z;
            p = atomicAdd(&fill[d.w], 1); col[p] = sv.w;
        }
    } else {
        int gid = (bx / 3) * 2 + rem;
        int n0 = (gid & 3) * 128;
        int m0 = (gid >> 2) * 128;
        gemm_body<true>(A, Bt, biasL, biasR, C, K, m0, n0, smem);
    }
}

// ---------------- standalone GEMM (layer 2, bf16 A) ----------------
__global__ __launch_bounds__(256) void k_gemm2(const bf16* __restrict__ A,
                                               const bf16* __restrict__ Bt,
                                               const float* __restrict__ biasL,
                                               const float* __restrict__ biasR,
                                               bf16* __restrict__ C, int K) {
    __shared__ bf16 smem[17408];
    int n0 = blockIdx.x * 128;
    int m0 = blockIdx.y * 128;
    gemm_body<false>(A, Bt, biasL, biasR, C, K, m0, n0, smem);
}

// ---------------- GATv2 aggregation: half-wave per edge, 8 ch/lane, packed fp32 math ----------
// One wave per dst node. Lanes 0-31 = item a, 32-63 = item b of each pair.
// Within a half: 8 lanes per head (hl>>3), 8 channels per lane ((hl&7)*8) = 4 float2 pairs.
// Item 0 = self-loop. Max-free softmax (logits bounded), leaky = 0.6u + 0.4|u| folded into att.
__global__ __launch_bounds__(256) void k_agg(const bf16* __restrict__ xlr,
                                             const float* __restrict__ att,
                                             const int* __restrict__ row_ptr,
                                             const int* __restrict__ col,
                                             const float* __restrict__ bias,
                                             bf16* __restrict__ out, int do_gelu) {
    int wave = threadIdx.x >> 6, lane = threadIdx.x & 63;
    int i = blockIdx.x * 4 + wave;
    int hl = lane & 31;
    int half = lane >> 5;
    unsigned f = (hl >> 3) * 64 + (hl & 7) * 8;

    floatx2 att6v[4], att4v[4], xrv[4];
    {
        floatx4 a0 = *(const floatx4*)(att + f);
        floatx4 a1 = *(const floatx4*)(att + f + 4);
        att6v[0] = (floatx2){0.6f * a0[0], 0.6f * a0[1]};
        att6v[1] = (floatx2){0.6f * a0[2], 0.6f * a0[3]};
        att6v[2] = (floatx2){0.6f * a1[0], 0.6f * a1[1]};
        att6v[3] = (floatx2){0.6f * a1[2], 0.6f * a1[3]};
        att4v[0] = (floatx2){0.4f * a0[0], 0.4f * a0[1]};
        att4v[1] = (floatx2){0.4f * a0[2], 0.4f * a0[3]};
        att4v[2] = (floatx2){0.4f * a1[0], 0.4f * a1[1]};
        att4v[3] = (floatx2){0.4f * a1[2], 0.4f * a1[3]};
        unsigned raw[4];
        *(uint4*)raw = *(const uint4*)(xlr + ((unsigned)i * 512u + 256u + f));
        #pragma unroll
        for (int k = 0; k < 4; k++) xrv[k] = cvt2(raw[k]);
    }

    int e0 = row_ptr[i], e1 = row_ptr[i + 1];
    int total = 1 + (e1 - e0);   // self + in-edges

    int src_c = i;
    if (half == 1 && total > 1) src_c = col[e0];
    unsigned g_cur[4];
    *(uint4*)g_cur = *(const uint4*)(xlr + ((unsigned)src_c * 512u + f));
    int t1 = 2 + half;
    int src_n = (t1 < total) ? col[e0 + t1 - 1] : i;

    float s = 0.f;
    floatx2 acc2[4] = {};

    for (int base = 0; base < total; base += 2) {
        unsigned g_nxt[4];
        *(uint4*)g_nxt = *(const uint4*)(xlr + ((unsigned)src_n * 512u + f));
        int t2 = base + 4 + half;
        int src_n2 = (t2 < total) ? col[e0 + t2 - 1] : i;
        bool valid = (base + half) < total;
        floatx2 xv[4], l2 = {0.f, 0.f};
        #pragma unroll
        for (int k = 0; k < 4; k++) {
            xv[k] = cvt2(g_cur[k]);
            floatx2 u = xv[k] + xrv[k];           // v_pk_add_f32
            floatx2 au = __builtin_elementwise_abs(u);
            l2 += u * att6v[k];                   // v_pk_fma_f32
            l2 += au * att4v[k];                  // v_pk_fma_f32
        }
        float l = l2.x + l2.y;
        l += __shfl_xor(l, 1, 8);
        l += __shfl_xor(l, 2, 8);
        l += __shfl_xor(l, 4, 8);
        float p = valid ? __expf(l) : 0.f;
        s += p;
        floatx2 p2 = {p, p};
        #pragma unroll
        for (int k = 0; k < 4; k++) acc2[k] += p2 * xv[k];   // v_pk_fma_f32
        #pragma unroll
        for (int k = 0; k < 4; k++) g_cur[k] = g_nxt[k];
        src_n = src_n2;
    }

    // combine the two halves
    s += __shfl_xor(s, 32, 64);
    #pragma unroll
    for (int k = 0; k < 4; k++) {
        acc2[k].x += __shfl_xor(acc2[k].x, 32, 64);
        acc2[k].y += __shfl_xor(acc2[k].y, 32, 64);
    }

    if (half == 0) {
        float inv = 1.0f / (s + 1e-16f);
        bf16 ov[8];
        #pragma unroll
        for (int k = 0; k < 4; k++) {
            float v0 = acc2[k].x * inv + bias[f + 2 * k];
            float v1 = acc2[k].y * inv + bias[f + 2 * k + 1];
            if (do_gelu) { v0 = gelu_f(v0); v1 = gelu_f(v1); }
            ov[2 * k]     = f2b(v0);
            ov[2 * k + 1] = f2b(v1);
        }
        *(short8*)(out + ((unsigned)i * 256u + f)) = *(const short8*)ov;
    }
}

// ---------------- shared head-layer body (block = one (graph, 64-col chunk)) ----------------
__device__ __forceinline__ void head_body(const bf16* __restrict__ inB,
                                          const float* __restrict__ inF,
                                          const float* __restrict__ W,
                                          const float* __restrict__ bias,
                                          float* __restrict__ out,
                                          int K, int N, long long row_stride, int act,
                                          int g, int chunk, float* zin, float* red) {
    int t = threadIdx.x;
    int nc = t & 63;
    int kq = t >> 6;
    int n = chunk * 64 + nc;
    for (int k = t; k < K; k += 256)
        zin[k] = inB ? b2f(inB[(size_t)g * row_stride + k])
                     : inF[(size_t)g * row_stride + k];
    __syncthreads();
    const int klen = K >> 2;
    const int kb = kq * klen;
    float acc = 0.f;
    #pragma unroll 8
    for (int k = 0; k < klen; k++)
        acc = fmaf(zin[kb + k], W[(size_t)(kb + k) * N + n], acc);
    red[t] = acc;
    __syncthreads();
    if (kq == 0) {
        float v = red[nc] + red[nc + 64] + red[nc + 128] + red[nc + 192] + bias[n];
        if (act) v = gelu_f(v);
        out[(size_t)g * N + n] = v;
    }
}

// ---------------- fused: pool stage 1 (blocks 0..511) + head lin1 (512..1535) ----------------
__global__ __launch_bounds__(256) void k_pe1(const bf16* __restrict__ hb,
                                             float* __restrict__ part,
                                             const float* __restrict__ lin1w,
                                             const float* __restrict__ lin1b,
                                             float* __restrict__ t1, int PG) {
    __shared__ float zin[256];
    __shared__ float red[256];
    int bx = blockIdx.x;
    if (bx < 512) {
        int g = bx >> 3, p = bx & 7, c = threadIdx.x;
        int rows_per = PG / 8;
        const bf16* base = hb + ((size_t)g * PG + (size_t)p * rows_per) * 256;
        float acc = 0.f;
        for (int r = 0; r < rows_per; r++) acc += b2f(base[(size_t)r * 256 + c]);
        part[((size_t)g * 8 + p) * 256 + c] = acc;
    } else {
        int b = bx - 512;
        head_body(hb, nullptr, lin1w, lin1b, t1, 256, 1024,
                  (long long)PG * 256, 1, b >> 4, b & 15, zin, red);
    }
}

// ---------------- fused: pool stage 2 (blocks 0..63) + head lin2 (64..319) ----------------
__global__ __launch_bounds__(256) void k_pe2(const float* __restrict__ part,
                                             float* __restrict__ outPool, int PG,
                                             const float* __restrict__ t1,
                                             const float* __restrict__ lin2w,
                                             const float* __restrict__ lin2b,
                                             float* __restrict__ t2) {
    __shared__ float zin[1024];
    __shared__ float red[256];
    int bx = blockIdx.x;
    if (bx < 64) {
        int g = bx, c = threadIdx.x;
        float acc = 0.f;
        for (int p = 0; p < 8; p++) acc += part[((size_t)g * 8 + p) * 256 + c];
        outPool[g * 256 + c] = acc / (float)PG;
    } else {
        int b = bx - 64;
        head_body(nullptr, t1, lin2w, lin2b, t2, 1024, 256,
                  1024, 0, b >> 2, b & 3, zin, red);
    }
}

// ---------------- final head layer ----------------
__global__ __launch_bounds__(256) void k_fin(const float* __restrict__ t2,
                                             const float* __restrict__ finw,
                                             const float* __restrict__ finb,
                                             float* __restrict__ out) {
    __shared__ float zin[256];
    __shared__ float red[256];
    head_body(nullptr, t2, finw, finb, out, 256, 512,
              256, 0, blockIdx.x, blockIdx.y, zin, red);
}

extern "C" void kernel_launch(void* const* d_in, const int* in_sizes, int n_in,
                              void* d_out, int out_size, void* d_ws, size_t ws_size,
                              hipStream_t stream) {
    const float* x     = (const float*)d_in[0];
    const int*   ei    = (const int*)d_in[1];
    const float* w1_l  = (const float*)d_in[4];
    const float* b1_l  = (const float*)d_in[5];
    const float* w1_r  = (const float*)d_in[6];
    const float* b1_r  = (const float*)d_in[7];
    const float* att1  = (const float*)d_in[8];
    const float* bias1 = (const float*)d_in[9];
    const float* w2_l  = (const float*)d_in[10];
    const float* b2_l  = (const float*)d_in[11];
    const float* w2_r  = (const float*)d_in[12];
    const float* b2_r  = (const float*)d_in[13];
    const float* att2  = (const float*)d_in[14];
    const float* bias2 = (const float*)d_in[15];
    const float* lin1w = (const float*)d_in[16];
    const float* lin1b = (const float*)d_in[17];
    const float* lin2w = (const float*)d_in[18];
    const float* lin2b = (const float*)d_in[19];
    const float* finw  = (const float*)d_in[20];
    const float* finb  = (const float*)d_in[21];

    const int N  = in_sizes[0] / 256;   // 32768
    const int E  = in_sizes[1] / 2;     // 524288
    const int NG = 64;
    const int PG = N / NG;              // 512

    // workspace layout (~52.5 MiB)
    char* ws = (char*)d_ws;
    size_t off = 0;
    bf16* xlr = (bf16*)(ws + off); off += (size_t)N * 512 * 2;    // 32 MiB [xl|xr]
    bf16* hb  = (bf16*)(ws + off); off += (size_t)N * 256 * 2;    // 16 MiB (h1 then h2)
    bf16* wt  = (bf16*)(ws + off); off += 2 * 512 * 256 * 2;      // 512 KiB both layers' Wt
    int* row_ptr = (int*)(ws + off); off += (size_t)(N + 4) * 4;
    int* cnt     = (int*)(ws + off); off += (size_t)N * 4;
    int* fill    = (int*)(ws + off); off += (size_t)N * 4;
    int* col     = (int*)(ws + off); off += (size_t)E * 4;
    float* pws   = (float*)(ws + off); off += (size_t)NG * 8 * 256 * 4;  // pool partials
    float* t1    = (float*)(ws + off); off += (size_t)NG * 1024 * 4;
    float* t2    = (float*)(ws + off); off += (size_t)NG * 256 * 4;

    const int* srcv = ei;
    const int* dstv = ei + E;

    // --- CSR count + weight transposes (one launch) ---
    hipMemsetAsync(cnt, 0, (size_t)N * 4, stream);
    k_count_tr<<<512 + 1024, 256, 0, stream>>>(dstv, cnt, E,
                                               w1_l, w1_r, w2_l, w2_r, wt);
    k_scan<<<1, 1024, 0, stream>>>(cnt, row_ptr, fill, N);

    // --- scatter + layer-1 GEMM (one union launch, roles interleaved) ---
    k_scatter_gemm<<<512 + 1024, 256, 0, stream>>>(srcv, dstv, fill, col, E,
                                                   x, wt, b1_l, b1_r, xlr, 256);
    k_agg<<<N / 4, 256, 0, stream>>>(xlr, att1, row_ptr, col, bias1, hb, 1);  // + GELU

    // --- layer 2 (A = h1 bf16) ---
    dim3 gg(4, N / 128);
    k_gemm2<<<gg, 256, 0, stream>>>(hb, wt + 512 * 256, b2_l, b2_r, xlr, 256);
    k_agg<<<N / 4, 256, 0, stream>>>(xlr, att2, row_ptr, col, bias2, hb, 0);  // h2

    float* outp = (float*)d_out;
    // --- pool1 + head lin1 (one launch) ---
    k_pe1<<<512 + 1024, 256, 0, stream>>>(hb, pws, lin1w, lin1b, t1, PG);
    // --- pool2 (-> d_out[64*512..]) + head lin2 (one launch) ---
    k_pe2<<<64 + 256, 256, 0, stream>>>(pws, outp + 64 * 512, PG, t1, lin2w, lin2b, t2);
    // --- final head layer -> d_out[0..64*512) ---
    dim3 gf(NG, 512 / 64);
    k_fin<<<gf, 256, 0, stream>>>(t2, finw, finb, outp);
}